// Round 11
// baseline (1437.244 us; speedup 1.0000x reference)
//
#include <hip/hip_runtime.h>
#include <math.h>

using short8 = __attribute__((ext_vector_type(8))) short;
using f32x4  = __attribute__((ext_vector_type(4))) float;
using ushort_t = unsigned short;

__device__ __forceinline__ ushort_t f2b(float f){
  unsigned int u = __builtin_bit_cast(unsigned int, f);
  u = (u + 0x7fffu + ((u >> 16) & 1u)) >> 16;
  return (ushort_t)u;
}
__device__ __forceinline__ float b2f(ushort_t u){
  unsigned int v = ((unsigned int)u) << 16;
  return __builtin_bit_cast(float, v);
}
__device__ __forceinline__ uint2 pk4(float a, float b, float c, float d){
  uint2 p; p.x = (unsigned)f2b(a) | ((unsigned)f2b(b)<<16);
  p.y = (unsigned)f2b(c) | ((unsigned)f2b(d)<<16); return p;
}
__device__ __forceinline__ uint2 z2(){ return uint2{0u,0u}; }
// HW packed f32->bf16 convert (RTNE): dst.lo16=bf16(lo), dst.hi16=bf16(hi)
__device__ __forceinline__ unsigned cvtpk(float lo, float hi){
  unsigned r; asm("v_cvt_pk_bf16_f32 %0, %1, %2" : "=v"(r) : "v"(lo), "v"(hi));
  return r;
}

__device__ __forceinline__ float fsig(float x){ return 1.f/(1.f+__expf(-x)); }
__device__ __forceinline__ float ftanh(float x){ return 1.f - 2.f/(1.f+__expf(2.f*x)); }
__device__ __forceinline__ void unp8(uint4 v, float* d){
  d[0]=b2f((ushort_t)(v.x&0xffffu)); d[1]=b2f((ushort_t)(v.x>>16));
  d[2]=b2f((ushort_t)(v.y&0xffffu)); d[3]=b2f((ushort_t)(v.y>>16));
  d[4]=b2f((ushort_t)(v.z&0xffffu)); d[5]=b2f((ushort_t)(v.z>>16));
  d[6]=b2f((ushort_t)(v.w&0xffffu)); d[7]=b2f((ushort_t)(v.w>>16));
}
__device__ __forceinline__ float4 unpk4f(uint2 v){
  float4 r;
  r.x = b2f((ushort_t)(v.x & 0xffffu)); r.y = b2f((ushort_t)(v.x >> 16));
  r.z = b2f((ushort_t)(v.y & 0xffffu)); r.w = b2f((ushort_t)(v.y >> 16));
  return r;
}

// ---------------- A generators: load4p(r, k, K) -> 4 packed bf16 ----------------
struct AgF32 { const float* A; int lda;
  __device__ uint2 load4p(int r, int k, int K) const {
    const float* p = &A[(size_t)r*lda + k];
    if (k+3 < K) { float4 v = *(const float4*)p; return pk4(v.x,v.y,v.z,v.w); }
    float a=0,b=0,c=0,d=0;
    if (k   < K) a = p[0];
    if (k+1 < K) b = p[1];
    if (k+2 < K) c = p[2];
    if (k+3 < K) d = p[3];
    return pk4(a,b,c,d); } };
struct AgBf16p { const ushort_t* A; int lda;
  __device__ uint2 load4p(int r, int k, int K) const {
    const ushort_t* p = &A[(size_t)r*lda + k];
    if (k+3 < K) return *(const uint2*)p;
    ushort_t a=0,b=0,c=0,d=0;
    if (k   < K) a = p[0];
    if (k+1 < K) b = p[1];
    if (k+2 < K) c = p[2];
    if (k+3 < K) d = p[3];
    uint2 q; q.x = (unsigned)a | ((unsigned)b<<16); q.y = (unsigned)c | ((unsigned)d<<16);
    return q; } };
struct AgStackA { const float* adj; const ushort_t* s2;   // rows<500: adj f32; >=500: S2 bf16
  __device__ uint2 load4p(int r, int k, int K) const {
    if (r < 500) {
      float a=0,b=0,c=0,d=0;
      const float* p = adj + (size_t)r*500 + k;
      if (k+3 < K) { float4 v = *(const float4*)p; return pk4(v.x,v.y,v.z,v.w); }
      if (k   < K) a = p[0];
      if (k+1 < K) b = p[1];
      if (k+2 < K) c = p[2];
      if (k+3 < K) d = p[3];
      return pk4(a,b,c,d);
    }
    const ushort_t* p = s2 + (size_t)(r-500)*500 + k;
    if (k+3 < K) return *(const uint2*)p;
    ushort_t a=0,b=0,c=0,d=0;
    if (k   < K) a = p[0];
    if (k+1 < K) b = p[1];
    if (k+2 < K) c = p[2];
    if (k+3 < K) d = p[3];
    uint2 q; q.x = (unsigned)a | ((unsigned)b<<16); q.y = (unsigned)c | ((unsigned)d<<16);
    return q; } };
struct AgXrow { const float* x;  // row=bt*500+n, k=c : x[bt,c,n]
  __device__ uint2 load4p(int r, int k, int K) const {
    int bt = r/500, n = r - bt*500;
    const float* p = x + (size_t)bt*32000 + n;
    float a=0,b=0,c=0,d=0;
    if (k   < K) a = p[(size_t)k*500];
    if (k+1 < K) b = p[(size_t)(k+1)*500];
    if (k+2 < K) c = p[(size_t)(k+2)*500];
    if (k+3 < K) d = p[(size_t)(k+3)*500];
    return pk4(a,b,c,d); } };
struct AgConvB { const ushort_t* hs; // bf16 hs; rows bn*24+t, k = dt*128+c
  __device__ uint2 load4p(int r, int k, int) const {
    int t = r % 24; int dt = k >> 7; int c = k & 127; int t2 = t + dt - 1;
    if (t2 < 0 || t2 >= 24) return z2();
    return *(const uint2*)&hs[(size_t)(r + (t2 - t))*128 + c]; } };
struct AgTeAdd { const float* o2f; const float* te;
  __device__ uint2 load4p(int r, int k, int) const {
    float4 a = *(const float4*)&o2f[(size_t)r*128 + k];
    float4 b = *(const float4*)&te[(size_t)(r/500)*128 + k];
    return pk4(a.x+b.x, a.y+b.y, a.z+b.z, a.w+b.w); } };

// ---------------- B generators: load4p(c, k, K) ----------------
struct BgPk { const ushort_t* B; int ldb;   // packed bf16 [N][K], k-contiguous
  __device__ uint2 load4p(int c, int k, int K) const {
    const ushort_t* p = &B[(size_t)c*ldb + k];
    if (k+3 < K) return *(const uint2*)p;
    ushort_t a=0,b=0,cc=0,d=0;
    if (k   < K) a = p[0];
    if (k+1 < K) b = p[1];
    if (k+2 < K) cc = p[2];
    if (k+3 < K) d = p[3];
    uint2 q; q.x = (unsigned)a | ((unsigned)b<<16); q.y = (unsigned)cc | ((unsigned)d<<16);
    return q; } };
struct BgXTv { const float* x;   // B[k][c]=x[c*500+k]
  __device__ uint2 load4p(int c, int k, int K) const {
    const float* p = x + (size_t)c*500 + k;
    if (k+3 < K) { float4 v = *(const float4*)p; return pk4(v.x,v.y,v.z,v.w); }
    float a=0,b=0,cc=0,d=0;
    if (k   < K) a = p[0];
    if (k+1 < K) b = p[1];
    if (k+2 < K) cc = p[2];
    if (k+3 < K) d = p[3];
    return pk4(a,b,cc,d); } };
struct BgAdjB { const float* adj;   // B[k][c]=adj[k*500+c]
  __device__ uint2 load4p(int c, int k, int K) const {
    float a=0,b=0,cc=0,d=0;
    if (k   < K) a = adj[(size_t)k*500 + c];
    if (k+1 < K) b = adj[(size_t)(k+1)*500 + c];
    if (k+2 < K) cc = adj[(size_t)(k+2)*500 + c];
    if (k+3 < K) d = adj[(size_t)(k+3)*500 + c];
    return pk4(a,b,cc,d); } };
struct BgY0T { const ushort_t* t;   // Y0T [128][192*500]; col c = bt*128+o
  __device__ uint2 load4p(int c, int k, int K) const {
    const ushort_t* p = &t[((size_t)(c & 127)*192 + (c >> 7))*500 + k];
    if (k+3 < K) return *(const uint2*)p;
    ushort_t a=0,b=0,cc=0,d=0;
    if (k   < K) a = p[0];
    if (k+1 < K) b = p[1];
    if (k+2 < K) cc = p[2];
    if (k+3 < K) d = p[3];
    uint2 qq; qq.x = (unsigned)a | ((unsigned)b<<16); qq.y = (unsigned)cc | ((unsigned)d<<16);
    return qq; } };

// ---------------- epilogues ----------------
struct EpNone { __device__ float operator()(int, int, float a) const { return a; } };
struct EpS2   { __device__ float operator()(int r, int c, float a) const { return 2.f*a - (r==c ? 1.f : 0.f); } };
struct EpBias { const float* b;
  __device__ float operator()(int, int c, float a) const { return a + b[c]; } };
struct EpRes1 { const ushort_t* out1; const float* st; const float *g, *bb, *rb; float invM;
  __device__ float operator()(int r, int c, float a) const {
    float mean = st[c]*invM; float var = st[128+c]*invM - mean*mean;
    float rstd = rsqrtf(var + 1e-5f);
    float y = (b2f(out1[(size_t)r*128 + c]) - mean)*rstd*g[c] + bb[c];
    y = fmaxf(y, 0.f);
    return a + rb[c] + y; } };
struct EpRes2 { const float *r2b, *rw, *rcb;
  __device__ float operator()(int, int c, float a) const {
    float s = 0.f;
    #pragma unroll
    for (int t=0; t<24; ++t) s += rw[t];
    return a + s*r2b[c] + rcb[0]; } };

// ---------------- pipelined MFMA generator GEMM ----------------
// OMODE: 0 = f32 store, 1 = bf16 store,
//        2 = xgT-transposed bf16 write (C=64 cols/bt), 3 = same with C=128.
template<int OMODE, class AG, class BG, class EP>
__global__ __launch_bounds__(256)
void gemm_mfma(AG ag, BG bg, EP ep, void* Cv, int M, int N, int K, int ldc) {
  constexpr int LDA = 40;
  __shared__ ushort_t As[128*LDA];
  __shared__ ushort_t Bs[128*LDA];
  int tid = threadIdx.x;
  int lane = tid & 63, wave = tid >> 6;
  int wr = (wave >> 1) * 64, wc = (wave & 1) * 64;
  int q = lane >> 4, r16 = lane & 15;
  int row0 = blockIdx.y*128, col0 = blockIdx.x*128;
  int am = tid >> 3, ak = (tid & 7) * 4;
  uint2 ua[4], ub[4];
  int nK = (K + 31) / 32;
  #pragma unroll
  for (int s=0;s<4;++s){
    int gr = row0 + am + 32*s;
    ua[s] = (gr < M) ? ag.load4p(gr, ak, K) : z2();
    int gc = col0 + am + 32*s;
    ub[s] = (gc < N) ? bg.load4p(gc, ak, K) : z2();
  }
  f32x4 acc[4][4] = {};
  for (int t=0; t<nK; ++t) {
    #pragma unroll
    for (int s=0;s<4;++s){
      *(uint2*)&As[(am + 32*s)*LDA + ak] = ua[s];
      *(uint2*)&Bs[(am + 32*s)*LDA + ak] = ub[s];
    }
    __syncthreads();
    if (t+1 < nK) {
      int k0 = (t+1)*32;
      #pragma unroll
      for (int s=0;s<4;++s){
        int gr = row0 + am + 32*s;
        ua[s] = (gr < M) ? ag.load4p(gr, k0+ak, K) : z2();
        int gc = col0 + am + 32*s;
        ub[s] = (gc < N) ? bg.load4p(gc, k0+ak, K) : z2();
      }
    }
    short8 a[4], b[4];
    #pragma unroll
    for (int it=0;it<4;++it) a[it] = *(const short8*)&As[(wr + it*16 + r16)*LDA + q*8];
    #pragma unroll
    for (int jt=0;jt<4;++jt) b[jt] = *(const short8*)&Bs[(wc + jt*16 + r16)*LDA + q*8];
    #pragma unroll
    for (int it=0;it<4;++it)
      #pragma unroll
      for (int jt=0;jt<4;++jt)
        acc[it][jt] = __builtin_amdgcn_mfma_f32_16x16x32_bf16(a[it], b[jt], acc[it][jt], 0, 0, 0);
    __syncthreads();
  }
  if constexpr (OMODE >= 2) {
    constexpr int CC = (OMODE == 2) ? 64 : 128;
    #pragma unroll
    for (int it=0;it<4;++it) {
      int rr0 = row0 + wr + it*16 + q*4;
      if (rr0 >= M) continue;
      int half = (rr0 >= 500) ? 1 : 0;
      int n0 = rr0 - half*500;
      #pragma unroll
      for (int jt=0;jt<4;++jt) {
        int c = col0 + wc + jt*16 + r16;
        if (c >= N) continue;
        int cin = c & (CC-1); int bt = c / CC;
        size_t addr = (size_t)(half*CC + cin)*96000 + (size_t)bt*500 + n0;
        *(uint2*)&((ushort_t*)Cv)[addr] =
            pk4(acc[it][jt][0], acc[it][jt][1], acc[it][jt][2], acc[it][jt][3]);
      }
    }
  } else {
    #pragma unroll
    for (int it=0;it<4;++it) {
      #pragma unroll
      for (int v=0;v<4;++v) {
        int rr = row0 + wr + it*16 + q*4 + v;
        if (rr >= M) continue;
        #pragma unroll
        for (int jt=0;jt<4;++jt) {
          int c = col0 + wc + jt*16 + r16;
          if (c >= N) continue;
          float val = ep(rr, c, acc[it][jt][v]);
          if (OMODE == 1) ((ushort_t*)Cv)[(size_t)rr*ldc + c] = f2b(val);
          else            ((float*)Cv)[(size_t)rr*ldc + c] = val;
        }
      }
    }
  }
}

// ---------------- LDS-free barrier-free flex GEMM ----------------
template<bool XSRC, bool BOUT>
__global__ __launch_bounds__(256, 3)
void k_flex(const float* x, const ushort_t* xgT, const ushort_t* wpf,
            const float* ne, const float* bp, void* Cv, int nKC) {
  int tid = threadIdx.x;
  int lane = tid & 63, wave = tid >> 6;
  int wr = (wave >> 1) * 64, wc = (wave & 1) * 64;
  int q = lane >> 4, r16 = lane & 15;
  int row0 = blockIdx.x * 128;
  int rowIt[4]; size_t xoff[4];
  float ne8[4][8];
  #pragma unroll
  for (int it=0; it<4; ++it) {
    int r = row0 + wr + it*16 + r16;
    rowIt[it] = r;
    if (XSRC) { int bt = r/500; int n = r - bt*500; xoff[it] = (size_t)bt*32000 + n; }
    float4 p0 = *(const float4*)&ne[(size_t)r*8];
    float4 p1 = *(const float4*)&ne[(size_t)r*8 + 4];
    ne8[it][0]=p0.x; ne8[it][1]=p0.y; ne8[it][2]=p0.z; ne8[it][3]=p0.w;
    ne8[it][4]=p1.x; ne8[it][5]=p1.y; ne8[it][6]=p1.z; ne8[it][7]=p1.w;
  }
  int cB = wc + r16;
  f32x4 acc[4][4] = {};
  int nT = nKC >> 2;
  float vc[4]; uint4 bc[4];
  {
    int kc = q;
    #pragma unroll
    for (int jt=0;jt<4;++jt)
      bc[jt] = *(const uint4*)&wpf[((size_t)kc*128 + cB + jt*16)*8];
    #pragma unroll
    for (int it=0;it<4;++it) {
      if (XSRC) vc[it] = x[xoff[it] + (size_t)kc*500];
      else      vc[it] = b2f(xgT[(size_t)kc*96000 + rowIt[it]]);
    }
  }
  for (int t=0; t<nT; ++t) {
    float vn[4]; uint4 bnx[4];
    if (t+1 < nT) {
      int kc = (t+1)*4 + q;
      #pragma unroll
      for (int jt=0;jt<4;++jt)
        bnx[jt] = *(const uint4*)&wpf[((size_t)kc*128 + cB + jt*16)*8];
      bool fromX = XSRC && (kc < 64);
      if (fromX) {
        #pragma unroll
        for (int it=0;it<4;++it) vn[it] = x[xoff[it] + (size_t)kc*500];
      } else {
        int kcx = XSRC ? (kc - 64) : kc;
        #pragma unroll
        for (int it=0;it<4;++it) vn[it] = b2f(xgT[(size_t)kcx*96000 + rowIt[it]]);
      }
    } else {
      #pragma unroll
      for (int it=0;it<4;++it) vn[it] = 0.f;
      #pragma unroll
      for (int jt=0;jt<4;++jt) { bnx[jt].x=0u; bnx[jt].y=0u; bnx[jt].z=0u; bnx[jt].w=0u; }
    }
    short8 a[4], b[4];
    #pragma unroll
    for (int jt=0;jt<4;++jt) b[jt] = __builtin_bit_cast(short8, bc[jt]);
    #pragma unroll
    for (int it=0;it<4;++it) {
      float v = vc[it];
      uint4 pw;
      pw.x = cvtpk(v*ne8[it][0], v*ne8[it][1]);
      pw.y = cvtpk(v*ne8[it][2], v*ne8[it][3]);
      pw.z = cvtpk(v*ne8[it][4], v*ne8[it][5]);
      pw.w = cvtpk(v*ne8[it][6], v*ne8[it][7]);
      a[it] = __builtin_bit_cast(short8, pw);
    }
    #pragma unroll
    for (int it=0;it<4;++it)
      #pragma unroll
      for (int jt=0;jt<4;++jt)
        acc[it][jt] = __builtin_amdgcn_mfma_f32_16x16x32_bf16(a[it], b[jt], acc[it][jt], 0, 0, 0);
    #pragma unroll
    for (int it=0;it<4;++it) vc[it] = vn[it];
    #pragma unroll
    for (int jt=0;jt<4;++jt) bc[jt] = bnx[jt];
  }
  #pragma unroll
  for (int it=0;it<4;++it) {
    #pragma unroll
    for (int v=0;v<4;++v) {
      int rr = row0 + wr + it*16 + q*4 + v;
      #pragma unroll
      for (int jt=0;jt<4;++jt) {
        int c = wc + jt*16 + r16;
        float val = acc[it][jt][v];
        #pragma unroll
        for (int d=0; d<8; ++d) val += ne[(size_t)rr*8 + d]*bp[d*128 + c];
        if (BOUT) ((ushort_t*)Cv)[(size_t)rr*128 + c] = f2b(val);
        else      ((float*)Cv)[(size_t)rr*128 + c] = val;
      }
    }
  }
}

// ---------------- packing kernels ----------------
__global__ void k_pack_bf(const float* s, ushort_t* d, int n){
  int i = blockIdx.x*256 + threadIdx.x; if (i < n) d[i] = f2b(s[i]); }
// fragment-order pack: d[(kc*128+c)*8+e] = wp[d=e][kk][cin][c], kk=kc/C cin=kc%C
__global__ void k_pack_wpf(const float* wp, ushort_t* d, int C, int KC){
  int i = blockIdx.x*256 + threadIdx.x; int total = KC*128*8; if (i >= total) return;
  int e = i & 7; int rest = i >> 3; int c = rest & 127; int kc = rest >> 7;
  int kk = kc / C; int cin = kc - kk*C;
  d[i] = f2b(wp[(((size_t)e*3 + kk)*C + cin)*128 + c]); }
__global__ void k_pack_qkvw(const float* cqw, const float* ckw, const float* vw, ushort_t* d){
  int i = blockIdx.x*256 + threadIdx.x; if (i >= 147456) return;
  int o = i / 384; int r = i - o*384; int dt = r >> 7; int cin = r & 127;
  float v;
  if (o < 128) v = cqw[((size_t)o*128 + cin)*3 + dt];
  else if (o < 256) v = ckw[((size_t)(o-128)*128 + cin)*3 + dt];
  else v = (dt==1) ? vw[(size_t)(o-256)*128 + cin] : 0.f;
  d[i] = f2b(v); }
__global__ void k_pack_qkvb(const float* cqb, const float* ckb, const float* vb, float* d){
  int i = threadIdx.x; // 384
  d[i] = (i<128) ? cqb[i] : (i<256) ? ckb[i-128] : vb[i-256]; }

// ---------------- small kernels ----------------
// Fused Phase-B: read RAW out0, apply BN0+relu, write Y0T [o][bt][n] (= xgT1 rows 0..127)
// and pooled partial sums (atomic).
__global__ void k_fuseB(const float* out0, const float* st, const float* g, const float* b,
                        ushort_t* y0t, float* pooled) {
  __shared__ float tile[32][33];
  __shared__ float red[8][32];
  int bt = blockIdx.z; int n0 = blockIdx.x*32; int o0 = blockIdx.y*32;
  int tx = threadIdx.x, ty = threadIdx.y;  // 32x8
  int o = o0 + tx;
  float mean = st[o]*(1.f/96000.f);
  float var  = st[128+o]*(1.f/96000.f) - mean*mean;
  float sc = rsqrtf(var + 1e-5f)*g[o];
  float bb = b[o] - mean*sc;
  float psum = 0.f;
  for (int i = ty; i < 32; i += 8) {
    int n = n0 + i;
    float y = 0.f;
    if (n < 500) {
      float v = out0[((size_t)bt*500 + n)*128 + o];
      y = fmaxf(v*sc + bb, 0.f);
      psum += y;
    }
    tile[i][tx] = y;
  }
  red[ty][tx] = psum;
  __syncthreads();
  if (ty == 0) {
    float s = red[0][tx];
    #pragma unroll
    for (int k=1;k<8;++k) s += red[k][tx];
    atomicAdd(&pooled[bt*128 + o], s*(1.f/500.f));
  }
  for (int i = ty; i < 32; i += 8) {
    int oo = o0 + i; int n = n0 + tx;
    if (n < 500) y0t[(size_t)oo*96000 + (size_t)bt*500 + n] = f2b(tile[tx][i]);
  }
}

__global__ void k_pool0(const float* x, float* pooled) {
  int bt = blockIdx.x; int c = threadIdx.x;
  const float* p = x + (size_t)bt*32000 + (size_t)c*500;
  float s = 0.f;
  for (int n=0;n<500;++n) s += p[n];
  pooled[bt*64 + c] = s*(1.f/500.f);
}

__global__ void k_mlp(const float* pooled, int F, const float* f1w, const float* f1b,
                      const float* f2w, const float* f2b, float* aout) {
  int bt = threadIdx.x;
  if (bt >= 192) return;
  float h[8];
  for (int k=0;k<8;++k){
    float s = f1b[k];
    for (int c=0;c<F;++c) s += pooled[bt*F + c]*f1w[k*F + c];
    h[k] = fmaxf(s, 0.f);
  }
  float z[8]; float m = -1e30f;
  for (int k2=0;k2<8;++k2){
    float s = f2b[k2];
    for (int k=0;k<8;++k) s += h[k]*f2w[k2*8 + k];
    z[k2] = s; m = fmaxf(m, s);
  }
  float den = 0.f;
  for (int k2=0;k2<8;++k2){ z[k2] = expf(z[k2]-m); den += z[k2]; }
  float inv = 1.f/den;
  for (int k2=0;k2<8;++k2) aout[bt*8 + k2] = z[k2]*inv;
}

__global__ void k_ne(const float* a, const float* emb, float* ne) {
  int i = blockIdx.x*256 + threadIdx.x;
  if (i >= 768000) return;
  int d = i & 7; int rem = i >> 3; int n = rem % 500; int bt = rem / 500;
  float s = 0.f;
  #pragma unroll
  for (int k=0;k<8;++k) s += a[bt*8 + k]*emb[((size_t)k*500 + n)*8 + d];
  ne[i] = s;
}

__global__ void k_bn_stats(const float* src, float* stats, int M, int rpb) {
  int col = threadIdx.x & 127; int seg = threadIdx.x >> 7;
  int r0 = blockIdx.x * rpb; int r1 = r0 + rpb; if (r1 > M) r1 = M;
  float s = 0.f, q = 0.f;
  for (int r = r0 + seg; r < r1; r += 2) {
    float v = src[(size_t)r*128 + col];
    s += v; q += v*v;
  }
  atomicAdd(&stats[col], s);
  atomicAdd(&stats[128+col], q);
}
__global__ void k_bn_stats_bf(const ushort_t* src, float* stats, int M, int rpb) {
  int col = threadIdx.x & 127; int seg = threadIdx.x >> 7;
  int r0 = blockIdx.x * rpb; int r1 = r0 + rpb; if (r1 > M) r1 = M;
  float s = 0.f, q = 0.f;
  for (int r = r0 + seg; r < r1; r += 2) {
    float v = b2f(src[(size_t)r*128 + col]);
    s += v; q += v*v;
  }
  atomicAdd(&stats[col], s);
  atomicAdd(&stats[128+col], q);
}

__global__ void k_bn_apply4(float* dst, const float* src, const float* st,
                            const float* g, const float* b, int total4, float invM, int relu, int addd) {
  int i = blockIdx.x*256 + threadIdx.x;
  if (i >= total4) return;
  int i4 = i*4; int c = i4 & 127;
  float4 sm = *(const float4*)&st[c];
  float4 sq = *(const float4*)&st[128+c];
  float4 g4 = *(const float4*)&g[c];
  float4 b4 = *(const float4*)&b[c];
  float4 v = *(const float4*)&src[i4];
  float4 y;
  {
    float mean = sm.x*invM; float var = sq.x*invM - mean*mean;
    y.x = (v.x-mean)*rsqrtf(var+1e-5f)*g4.x + b4.x;
    mean = sm.y*invM; var = sq.y*invM - mean*mean;
    y.y = (v.y-mean)*rsqrtf(var+1e-5f)*g4.y + b4.y;
    mean = sm.z*invM; var = sq.z*invM - mean*mean;
    y.z = (v.z-mean)*rsqrtf(var+1e-5f)*g4.z + b4.z;
    mean = sm.w*invM; var = sq.w*invM - mean*mean;
    y.w = (v.w-mean)*rsqrtf(var+1e-5f)*g4.w + b4.w;
  }
  if (relu){ y.x=fmaxf(y.x,0.f); y.y=fmaxf(y.y,0.f); y.z=fmaxf(y.z,0.f); y.w=fmaxf(y.w,0.f); }
  if (addd){ float4 d0 = *(const float4*)&dst[i4]; y.x+=d0.x; y.y+=d0.y; y.z+=d0.z; y.w+=d0.w; }
  *(float4*)&dst[i4] = y;
}

// in-place BN apply + relu on bf16 buffer
__global__ void k_bn_apply_bf_ip(ushort_t* buf, const float* st,
                                 const float* g, const float* b, int total4, float invM) {
  int i = blockIdx.x*256 + threadIdx.x;
  if (i >= total4) return;
  int i4 = i*4; int c = i4 & 127;
  uint2 vv = *(const uint2*)&buf[i4];
  float v0 = b2f((ushort_t)(vv.x & 0xffffu)), v1 = b2f((ushort_t)(vv.x >> 16));
  float v2 = b2f((ushort_t)(vv.y & 0xffffu)), v3 = b2f((ushort_t)(vv.y >> 16));
  float4 sm = *(const float4*)&st[c];
  float4 sq = *(const float4*)&st[128+c];
  float4 g4 = *(const float4*)&g[c];
  float4 b4 = *(const float4*)&b[c];
  float mean, var, y0, y1, y2, y3;
  mean = sm.x*invM; var = sq.x*invM - mean*mean;
  y0 = (v0-mean)*rsqrtf(var+1e-5f)*g4.x + b4.x;
  mean = sm.y*invM; var = sq.y*invM - mean*mean;
  y1 = (v1-mean)*rsqrtf(var+1e-5f)*g4.y + b4.y;
  mean = sm.z*invM; var = sq.z*invM - mean*mean;
  y2 = (v2-mean)*rsqrtf(var+1e-5f)*g4.z + b4.z;
  mean = sm.w*invM; var = sq.w*invM - mean*mean;
  y3 = (v3-mean)*rsqrtf(var+1e-5f)*g4.w + b4.w;
  y0=fmaxf(y0,0.f); y1=fmaxf(y1,0.f); y2=fmaxf(y2,0.f); y3=fmaxf(y3,0.f);
  *(uint2*)&buf[i4] = pk4(y0,y1,y2,y3);
}

// ---------------- MFMA recurrent GRU (+fused stats, bf16 hs out) ----------------
__global__ __launch_bounds__(256, 1) void k_gru_mfma(
    const ushort_t* gi, const ushort_t* whhp, const float* bhh,
    ushort_t* hsb, float* stats) {
  __shared__ ushort_t hbf[16*128];   // bf16 h, 16B-chunk XOR swizzled
  __shared__ float    uh[16*384];    // f32 uh, swizzled; reused as stats scratch

  int tid  = threadIdx.x;
  int lane = tid & 63;
  int wave = tid >> 6;
  int r16  = lane & 15, q = lane >> 4;

  short8 bfrag[6][4];
  #pragma unroll
  for (int j=0;j<6;++j){
    int col = (wave*6 + j)*16 + r16;
    #pragma unroll
    for (int kk=0;kk<4;++kk)
      bfrag[j][kk] = *(const short8*)&whhp[(size_t)col*128 + kk*32 + q*8];
  }

  int gr = tid >> 4;           // 0..15
  int gc = tid & 15;           // chunk index
  int u0 = gc*8;
  int s  = blockIdx.x*16 + gr;
  int b  = s / 500, n = s - b*500;
  size_t gi_base = ((size_t)b*24*500 + n)*384;   // + t*192000
  size_t hs_base = (size_t)s*24*128 + u0;        // + t*128 (bf16)

  float bh0[8], bh1[8], bh2[8];
  #pragma unroll
  for (int k=0;k<8;++k){ bh0[k]=bhh[u0+k]; bh1[k]=bhh[128+u0+k]; bh2[k]=bhh[256+u0+k]; }

  float h[8], sacc[8], qacc[8];
  #pragma unroll
  for (int k=0;k<8;++k){ h[k]=0.f; sacc[k]=0.f; qacc[k]=0.f; }
  {
    int phys = gr*128 + ((gc ^ (gr&7))*8);
    uint4 zz; zz.x=0u; zz.y=0u; zz.z=0u; zz.w=0u;
    *(uint4*)&hbf[phys] = zz;
  }

  for (int t=0;t<24;++t){
    __syncthreads();
    const ushort_t* gp = gi + gi_base + (size_t)t*192000;
    uint4 gir = *(const uint4*)&gp[u0];
    uint4 giz = *(const uint4*)&gp[128+u0];
    uint4 gin = *(const uint4*)&gp[256+u0];

    short8 afrag[4];
    #pragma unroll
    for (int kk=0;kk<4;++kk)
      afrag[kk] = *(const short8*)&hbf[r16*128 + (((kk<<2)+q) ^ (r16&7))*8];
    #pragma unroll
    for (int j=0;j<6;++j){
      f32x4 acc = {};
      #pragma unroll
      for (int kk=0;kk<4;++kk)
        acc = __builtin_amdgcn_mfma_f32_16x16x32_bf16(afrag[kk], bfrag[j][kk], acc, 0, 0, 0);
      int col = (wave*6+j)*16 + r16;
      #pragma unroll
      for (int v=0;v<4;++v){
        int rr = q*4 + v;
        uh[rr*384 + ((((col>>2) ^ (rr&7))<<2) | (col&3))] = acc[v];
      }
    }
    __syncthreads();

    float hr[8], hz[8], hn[8];
    {
      int rw = gr*384; int sw = gr & 7;
      int c0 = (u0>>2);
      float4 A, Bv;
      A  = *(const float4*)&uh[rw + ((c0      ^ sw)<<2)];
      Bv = *(const float4*)&uh[rw + (((c0+1)  ^ sw)<<2)];
      hr[0]=A.x; hr[1]=A.y; hr[2]=A.z; hr[3]=A.w; hr[4]=Bv.x; hr[5]=Bv.y; hr[6]=Bv.z; hr[7]=Bv.w;
      int c1 = ((128+u0)>>2);
      A  = *(const float4*)&uh[rw + ((c1      ^ sw)<<2)];
      Bv = *(const float4*)&uh[rw + (((c1+1)  ^ sw)<<2)];
      hz[0]=A.x; hz[1]=A.y; hz[2]=A.z; hz[3]=A.w; hz[4]=Bv.x; hz[5]=Bv.y; hz[6]=Bv.z; hz[7]=Bv.w;
      int c2 = ((256+u0)>>2);
      A  = *(const float4*)&uh[rw + ((c2      ^ sw)<<2)];
      Bv = *(const float4*)&uh[rw + (((c2+1)  ^ sw)<<2)];
      hn[0]=A.x; hn[1]=A.y; hn[2]=A.z; hn[3]=A.w; hn[4]=Bv.x; hn[5]=Bv.y; hn[6]=Bv.z; hn[7]=Bv.w;
    }
    float ir[8], iz[8], in_[8];
    unp8(gir, ir); unp8(giz, iz); unp8(gin, in_);
    #pragma unroll
    for (int k=0;k<8;++k){
      float rg = fsig(ir[k] + hr[k] + bh0[k]);
      float zg = fsig(iz[k] + hz[k] + bh1[k]);
      float ng = ftanh(in_[k] + rg*(hn[k] + bh2[k]));
      float hv = (1.f - zg)*ng + zg*h[k];
      h[k] = hv;
      sacc[k] += hv; qacc[k] += hv*hv;
    }
    uint2 p0 = pk4(h[0],h[1],h[2],h[3]);
    uint2 p1 = pk4(h[4],h[5],h[6],h[7]);
    uint4 pw; pw.x=p0.x; pw.y=p0.y; pw.z=p1.x; pw.w=p1.y;
    {
      int phys = gr*128 + ((gc ^ (gr&7))*8);
      *(uint4*)&hbf[phys] = pw;
    }
    *(uint4*)&hsb[hs_base + (size_t)t*128] = pw;
  }

  __syncthreads();
  #pragma unroll
  for (int k=0;k<8;++k) uh[gr*128 + u0 + k] = sacc[k];
  __syncthreads();
  if (tid < 128) {
    float ss = 0.f;
    for (int r=0;r<16;++r) ss += uh[r*128 + tid];
    atomicAdd(&stats[tid], ss);
  }
  __syncthreads();
  #pragma unroll
  for (int k=0;k<8;++k) uh[gr*128 + u0 + k] = qacc[k];
  __syncthreads();
  if (tid < 128) {
    float qq = 0.f;
    for (int r=0;r<16;++r) qq += uh[r*128 + tid];
    atomicAdd(&stats[128 + tid], qq);
  }
}

// attention over interleaved QKV [r][384] — bank-aligned pitch 128 + 16B-chunk XOR.
// Store elem (t,c) at A[t*128 + ((c>>2)^(t&7))*4 + (c&3)]. Pitch%32==0 so bank
// depends only on chunk^row-XOR: QK float4 reads span all 32 banks per 8 lanes
// (conflict-free); PV/xbar scalar/float4 patterns are 2-way max (free).
__global__ __launch_bounds__(256) void k_attn3(const ushort_t* QKV,
    const float* ow, const float* ob, const float* fcw, const float* fcb, float* out2f) {
  __shared__ float A1[24*128];
  __shared__ float A2[24*128];
  __shared__ float Sc[8][24][25];
  __shared__ float red[256];
  int bn = blockIdx.x; int tid = threadIdx.x;
  size_t base = (size_t)bn*9216;   // 24*384
  // load Q,K (vectorized: 4 elems/thread)
  for (int i=tid;i<768;i+=256){
    int t=i>>5, c4=i&31;
    uint2 q2 = *(const uint2*)&QKV[base + (size_t)t*384 + c4*4];
    uint2 k2 = *(const uint2*)&QKV[base + (size_t)t*384 + 128 + c4*4];
    int phys = t*128 + ((c4^(t&7))<<2);
    *(float4*)&A1[phys] = unpk4f(q2);
    *(float4*)&A2[phys] = unpk4f(k2);
  }
  __syncthreads();
  // QK^T
  for (int i=tid;i<4608;i+=256){
    int hh = i/576; int r = i - hh*576; int t = r/24; int s_ = r - t*24;
    float d0 = 0.f, d1 = 0.f;
    #pragma unroll
    for (int dd4=0;dd4<4;++dd4){
      float4 qv = *(const float4*)&A1[t*128 + ((((hh<<2)+dd4)^(t&7))<<2)];
      float4 kv = *(const float4*)&A2[s_*128 + ((((hh<<2)+dd4)^(s_&7))<<2)];
      d0 += qv.x*kv.x + qv.y*kv.y;
      d1 += qv.z*kv.z + qv.w*kv.w;
    }
    Sc[hh][t][s_] = (d0+d1)*0.25f;
  }
  __syncthreads();
  // load V into A2 (vectorized)
  for (int i=tid;i<768;i+=256){
    int t=i>>5, c4=i&31;
    uint2 v2 = *(const uint2*)&QKV[base + (size_t)t*384 + 256 + c4*4];
    *(float4*)&A2[t*128 + ((c4^(t&7))<<2)] = unpk4f(v2);
  }
  if (tid < 192) {
    int hh = tid/24, t = tid - (tid/24)*24;
    float m = -1e30f;
    for (int s_=0;s_<24;++s_) m = fmaxf(m, Sc[hh][t][s_]);
    float den = 0.f;
    for (int s_=0;s_<24;++s_){ float e = __expf(Sc[hh][t][s_]-m); Sc[hh][t][s_] = e; den += e; }
    float inv = 1.f/den;
    for (int s_=0;s_<24;++s_) Sc[hh][t][s_] *= inv;
  }
  __syncthreads();
  // PV (vectorized over o: 4 outputs/thread)
  for (int i=tid;i<768;i+=256){
    int t = i>>5; int o4 = i&31; int hh = o4>>2;
    float4 s = {0.f,0.f,0.f,0.f};
    #pragma unroll
    for (int s_=0;s_<24;++s_){
      float p = Sc[hh][t][s_];
      float4 v = *(const float4*)&A2[s_*128 + ((o4^(s_&7))<<2)];
      s.x += p*v.x; s.y += p*v.y; s.z += p*v.z; s.w += p*v.w;
    }
    *(float4*)&A1[t*128 + ((o4^(t&7))<<2)] = s;
  }
  __syncthreads();
  // xbar: 256-thread split reduction over t
  int o = tid & 127, hf = tid >> 7;
  {
    float s = 0.f;
    for (int t = hf*12; t < hf*12 + 12; ++t)
      s += fcw[t]*A1[t*128 + ((((o>>2)^(t&7))<<2) | (o&3))];
    red[tid] = s;
  }
  __syncthreads();
  float* xbar = &Sc[0][0][0];
  if (tid < 128) xbar[tid] = red[tid] + red[tid+128];
  __syncthreads();
  // ow: 256-thread split reduction over c
  {
    float s = 0.f;
    for (int c = hf*64; c < hf*64 + 64; ++c) s += xbar[c]*ow[o*128 + c];
    red[tid] = s;
  }
  __syncthreads();
  if (tid < 128) {
    float sfc = 0.f;
    for (int t=0;t<24;++t) sfc += fcw[t];
    out2f[(size_t)bn*128 + o] = red[tid] + red[tid+128] + sfc*ob[o] + fcb[0];
  }
}

__global__ void k_rbar_bf(const ushort_t* out2, const float* rw, float* rbar) {
  int i = blockIdx.x*256 + threadIdx.x;
  if (i >= 512000) return;
  int c = i & 127; int bnn = i >> 7; int b = bnn/500, n = bnn - b*500;
  float s = 0.f;
  #pragma unroll
  for (int t=0;t<24;++t) s += rw[t] * b2f(out2[((size_t)(b*24 + t)*500 + n)*128 + c]);
  rbar[i] = s;
}

__global__ void k_te(const float* tt, const float* w1, const float* b1,
                     const float* w2, const float* b2, float* te) {
  __shared__ float h1[128];
  int b = blockIdx.x; int o = threadIdx.x;
  float s = b1[o];
  for (int c=0;c<32;++c) s += tt[b*32 + c]*w1[o*32 + c];
  h1[o] = fmaxf(s, 0.f);
  __syncthreads();
  float s2 = b2[o];
  for (int c=0;c<128;++c) s2 += h1[c]*w2[o*128 + c];
  te[b*128 + o] = s2;
}

__global__ void k_grid(const float* gnm, const float* fin, float* out) {
  int e = threadIdx.x & 63; int gq = threadIdx.x >> 6;
  int g = blockIdx.x*4 + gq; int b = blockIdx.y;
  float s = 0.f;
  const float* gr = gnm + (size_t)g*500;
  const float* fb = fin + (size_t)b*500*64 + e;
  for (int n=0;n<500;++n) s += gr[n] * fb[(size_t)n*64];
  out[(size_t)b*32000 + (size_t)e*500 + g] = s;
}

// ---------------- launch ----------------
extern "C" void kernel_launch(void* const* d_in, const int* in_sizes, int n_in,
                              void* d_out, int out_size, void* d_ws, size_t ws_size,
                              hipStream_t stream) {
  const float* adj   = (const float*)d_in[0];
  const float* x     = (const float*)d_in[1];
  const float* gnm   = (const float*)d_in[2];
  const float* ttime = (const float*)d_in[3];
  const float* emb   = (const float*)d_in[4];
  const float* wp0   = (const float*)d_in[5];
  const float* bp0   = (const float*)d_in[6];
  const float* a0f1w = (const float*)d_in[7];
  const float* a0f1b = (const float*)d_in[8];
  const float* a0f2w = (const float*)d_in[9];
  const float* a0f2b = (const float*)d_in[10];
  const float* wp1   = (const float*)d_in[11];
  const float* bp1   = (const float*)d_in[12];
  const float* a1f1w = (const float*)d_in[13];
  const float* a1f1b = (const float*)d_in[14];
  const float* a1f2w = (const float*)d_in[15];
  const float* a1f2b = (const float*)d_in[16];
  const float* bn0g  = (const float*)d_in[17];
  const float* bn0b  = (const float*)d_in[18];
  const float* bn1g  = (const float*)d_in[19];
  const float* bn1b  = (const float*)d_in[20];
  const float* wih   = (const float*)d_in[21];
  const float* whh   = (const float*)d_in[22];
  const float* bih   = (const float*)d_in[23];
  const float* bhh   = (const float*)d_in[24];
  const float* bgg   = (const float*)d_in[25];
  const float* bgb   = (const float*)d_in[26];
  const float* cqw   = (const float*)d_in[27];
  const float* cqb   = (const float*)d_in[28];
  const float* ckw   = (const float*)d_in[29];
  const float* ckb   = (const float*)d_in[30];
  const float* vw    = (const float*)d_in[31];
  const float* vb    = (const float*)d_in[32];
  const float* ow    = (const float*)d_in[33];
  const float* ob    = (const float*)d_in[34];
  const float* r1w   = (const float*)d_in[35];
  const float* r1b   = (const float*)d_in[36];
  const float* fcw   = (const float*)d_in[37];
  const float* fcb   = (const float*)d_in[38];
  const float* rcw   = (const float*)d_in[39];
  const float* rcb   = (const float*)d_in[40];
  const float* r2w   = (const float*)d_in[41];
  const float* r2b   = (const float*)d_in[42];
  const float* bnrg  = (const float*)d_in[43];
  const float* bnrb  = (const float*)d_in[44];
  const float* te1w  = (const float*)d_in[45];
  const float* te1b  = (const float*)d_in[46];
  const float* te2w  = (const float*)d_in[47];
  const float* te2b  = (const float*)d_in[48];
  const float* finw  = (const float*)d_in[49];
  const float* finb  = (const float*)d_in[50];
  float* dout = (float*)d_out;
  float* W = (float*)d_ws;

  size_t off = 0;
  auto alloc = [&](size_t n){ size_t r = off; off += (n + 255) & ~(size_t)255; return r; };
  size_t oStats = alloc(512);
  size_t oPool  = alloc(24576);
  size_t oAmix  = alloc(1536);
  size_t oTe    = alloc(1024);
  size_t oO2f   = alloc(512000);
  size_t oRbar  = alloc(512000);
  size_t oRes   = alloc(512000);
  size_t oFin   = alloc(256000);
  size_t oNe0   = alloc(768000);
  size_t oNe1   = alloc(768000);
  size_t oS2    = alloc(125000);     // bf16 [500][500]
  size_t oWpf0  = alloc(98304);      // bf16 [192][128][8]
  size_t oWpf1  = alloc(196608);     // bf16 [384][128][8]
  size_t oR1wp  = alloc(4096);       // bf16 [128][64]
  size_t oWihp  = alloc(24576);      // bf16 [384][128]
  size_t oWhhp  = alloc(24576);      // bf16 [384][128]
  size_t oQkvw  = alloc(73728);      // bf16 [384][384]
  size_t oQkvb  = alloc(384);
  size_t oR2wp  = alloc(8192);
  size_t oFinwp = alloc(4096);
  size_t oR1    = alloc(12288000);   // out0 (f32) -> out2b (bf16)
  size_t oR2    = alloc(12288000);   // xgT1 low -> gi(low) -> QKV(low)
  size_t oR4    = alloc(6144000);    // xgT0 -> xgT1 high -> gi(high) -> QKV(high)
  size_t oOut1  = alloc(6144000);    // out1 -> hsb (bf16, in-place BN)
  (void)n_in; (void)in_sizes; (void)out_size;
  if (ws_size < off * sizeof(float)) return;

  float* stats = W + oStats;
  float* pooled= W + oPool;
  float* amix  = W + oAmix;
  float* teb   = W + oTe;
  float* out2f = W + oO2f;
  float* rbar  = W + oRbar;
  float* resout= W + oRes;
  float* fin   = W + oFin;
  float* ne0   = W + oNe0;
  float* ne1   = W + oNe1;
  ushort_t* S2bf  = (ushort_t*)(W + oS2);
  ushort_t* wpf0  = (ushort_t*)(W + oWpf0);
  ushort_t* wpf1  = (ushort_t*)(W + oWpf1);
  ushort_t* r1wp  = (ushort_t*)(W + oR1wp);
  ushort_t* wihp  = (ushort_t*)(W + oWihp);
  ushort_t* whhp  = (ushort_t*)(W + oWhhp);
  ushort_t* qkvwp = (ushort_t*)(W + oQkvw);
  float*    qkvb  = W + oQkvb;
  ushort_t* r2wp  = (ushort_t*)(W + oR2wp);
  ushort_t* finwp = (ushort_t*)(W + oFinwp);
  float* out0  = W + oR1;
  ushort_t* out2b = (ushort_t*)(W + oR1);    // after out0 dead
  ushort_t* xgT1 = (ushort_t*)(W + oR2);     // [384][96000] spans R2+R4 (contiguous)
  ushort_t* gi16 = (ushort_t*)(W + oR2);     // [96000][384] spans R2+R4
  ushort_t* qkv16= (ushort_t*)(W + oR2);     // same span (gi dead)
  ushort_t* xgT0 = (ushort_t*)(W + oR4);     // [128][96000] during phase A
  ushort_t* out1 = (ushort_t*)(W + oOut1);
  ushort_t* hsb  = (ushort_t*)(W + oOut1);   // after out1 dead

  // ---- weight packing ----
  k_pack_wpf<<<768, 256, 0, stream>>>(wp0, wpf0, 64, 192);
  k_pack_wpf<<<1536, 256, 0, stream>>>(wp1, wpf1, 128, 384);
  k_pack_bf<<<32, 256, 0, stream>>>(r1w, r1wp, 8192);
  k_pack_bf<<<192, 256, 0, stream>>>(wih, wihp, 49152);
  k_pack_bf<<<192, 256, 0, stream>>>(whh, whhp, 49152);
  k_pack_bf<<<64, 256, 0, stream>>>(r2w, r2wp, 16384);
  k_pack_bf<<<32, 256, 0, stream>>>(finw, finwp, 8192);
  k_pack_qkvw<<<576, 256, 0, stream>>>(cqw, ckw, vw, qkvwp);
  k_pack_qkvb<<<1, 384, 0, stream>>>(cqb, ckb, vb, qkvb);

  // ---- Phase A ----
  gemm_mfma<1><<<dim3(4,4), 256, 0, stream>>>(
      AgF32{adj,500}, BgAdjB{adj}, EpS2{}, (void*)S2bf, 500, 500, 500, 500);
  gemm_mfma<2><<<dim3(96,8), 256, 0, stream>>>(
      AgStackA{adj, S2bf}, BgXTv{x}, EpNone{}, (void*)xgT0, 1000, 12288, 500, 0);
  k_pool0<<<192, 64, 0, stream>>>(x, pooled);
  k_mlp<<<1, 192, 0, stream>>>(pooled, 64, a0f1w, a0f1b, a0f2w, a0f2b, amix);
  k_ne<<<3000, 256, 0, stream>>>(amix, emb, ne0);
  k_flex<true, false><<<750, 256, 0, stream>>>(
      x, xgT0, wpf0, ne0, bp0, (void*)out0, 192);
  hipMemsetAsync((void*)stats, 0, 256*sizeof(float), stream);
  k_bn_stats<<<768, 256, 0, stream>>>(out0, stats, 96000, 125);

  // ---- Phase B (fused BN0+relu -> Y0T(=xgT1 rows 0..127) + pooled) ----
  hipMemsetAsync((void*)pooled, 0, 24576*sizeof(float), stream);
  k_fuseB<<<dim3(16,4,192), dim3(32,8), 0, stream>>>(out0, stats, bn0g, bn0b, xgT1, pooled);
  k_mlp<<<1, 192, 0, stream>>>(pooled, 128, a1f1w, a1f1b, a1f2w, a1f2b, amix);
  k_ne<<<3000, 256, 0, stream>>>(amix, emb, ne1);
  gemm_mfma<3><<<dim3(192,8), 256, 0, stream>>>(
      AgStackA{adj, S2bf}, BgY0T{xgT1}, EpNone{},
      (void*)(xgT1 + (size_t)128*96000), 1000, 24576, 500, 0);
  k_flex<false, true><<<750, 256, 0, stream>>>(
      x, xgT1, wpf1, ne1, bp1, (void*)out1, 384);
  hipMemsetAsync((void*)stats, 0, 256*sizeof(float), stream);
  k_bn_stats_bf<<<768, 256, 0, stream>>>(out1, stats, 96000, 125);
  gemm_mfma<1><<<dim3(1,750), 256, 0, stream>>>(
      AgXrow{x}, BgPk{r1wp,64}, EpRes1{out1, stats, bn1g, bn1b, r1b, 1.f/96000.f},
      (void*)out2b, 96000, 128, 64, 128);

  // ---- Phase E-part1 (consumes out2b early) ----
  k_rbar_bf<<<2000, 256, 0, stream>>>(out2b, rcw, rbar);
  gemm_mfma<0><<<dim3(1,32), 256, 0, stream>>>(
      AgF32{rbar,128}, BgPk{r2wp,128}, EpRes2{r2b, rcw, rcb}, (void*)resout, 4000, 128, 128, 128);
  hipMemsetAsync((void*)stats, 0, 256*sizeof(float), stream);
  k_bn_stats<<<32, 256, 0, stream>>>(resout, stats, 4000, 125);

  // ---- Phase C: gi on MFMA + recurrent GRU (MFMA, fused stats, bf16 out) ----
  gemm_mfma<1><<<dim3(3,750), 256, 0, stream>>>(
      AgBf16p{out2b,128}, BgPk{wihp,128}, EpBias{bih}, (void*)gi16, 96000, 384, 128, 384);
  hipMemsetAsync((void*)(stats+256), 0, 256*sizeof(float), stream);
  k_gru_mfma<<<250, 256, 0, stream>>>(gi16, whhp, bhh, hsb, stats+256);
  k_bn_apply_bf_ip<<<12000, 256, 0, stream>>>(hsb, stats+256, bgg, bgb, 3072000, 1.f/96000.f);

  // ---- Phase D: one QKV GEMM + attention ----
  gemm_mfma<1><<<dim3(3,750), 256, 0, stream>>>(
      AgConvB{hsb}, BgPk{qkvwp,384}, EpBias{qkvb}, (void*)qkv16, 96000, 384, 384, 384);
  k_attn3<<<4000, 256, 0, stream>>>(qkv16, ow, ob, fcw, fcb, out2f);

  // ---- Phase E-part2 ----
  k_bn_apply4<<<500, 256, 0, stream>>>(out2f, resout, stats, bnrg, bnrb, 128000, 1.f/4000.f, 0, 1);
  k_te<<<8, 128, 0, stream>>>(ttime, te1w, te1b, te2w, te2b, teb);
  gemm_mfma<0><<<dim3(1,32), 256, 0, stream>>>(
      AgTeAdd{out2f, teb}, BgPk{finwp,128}, EpBias{finb}, (void*)fin, 4000, 64, 128, 64);
  k_grid<<<dim3(125,8), 256, 0, stream>>>(gnm, fin, dout);
}

// Round 12
// 1135.014 us; speedup vs baseline: 1.2663x; 1.2663x over previous
//
#include <hip/hip_runtime.h>
#include <math.h>

using short8 = __attribute__((ext_vector_type(8))) short;
using f32x4  = __attribute__((ext_vector_type(4))) float;
using ushort_t = unsigned short;

__device__ __forceinline__ ushort_t f2b(float f){
  unsigned int u = __builtin_bit_cast(unsigned int, f);
  u = (u + 0x7fffu + ((u >> 16) & 1u)) >> 16;
  return (ushort_t)u;
}
__device__ __forceinline__ float b2f(ushort_t u){
  unsigned int v = ((unsigned int)u) << 16;
  return __builtin_bit_cast(float, v);
}
__device__ __forceinline__ uint2 pk4(float a, float b, float c, float d){
  uint2 p; p.x = (unsigned)f2b(a) | ((unsigned)f2b(b)<<16);
  p.y = (unsigned)f2b(c) | ((unsigned)f2b(d)<<16); return p;
}
__device__ __forceinline__ uint2 z2(){ return uint2{0u,0u}; }
// HW packed f32->bf16 convert (RTNE): dst.lo16=bf16(lo), dst.hi16=bf16(hi)
__device__ __forceinline__ unsigned cvtpk(float lo, float hi){
  unsigned r; asm("v_cvt_pk_bf16_f32 %0, %1, %2" : "=v"(r) : "v"(lo), "v"(hi));
  return r;
}

__device__ __forceinline__ float fsig(float x){ return 1.f/(1.f+__expf(-x)); }
__device__ __forceinline__ float ftanh(float x){ return 1.f - 2.f/(1.f+__expf(2.f*x)); }
__device__ __forceinline__ void unp8(uint4 v, float* d){
  d[0]=b2f((ushort_t)(v.x&0xffffu)); d[1]=b2f((ushort_t)(v.x>>16));
  d[2]=b2f((ushort_t)(v.y&0xffffu)); d[3]=b2f((ushort_t)(v.y>>16));
  d[4]=b2f((ushort_t)(v.z&0xffffu)); d[5]=b2f((ushort_t)(v.z>>16));
  d[6]=b2f((ushort_t)(v.w&0xffffu)); d[7]=b2f((ushort_t)(v.w>>16));
}
__device__ __forceinline__ float4 unpk4f(uint2 v){
  float4 r;
  r.x = b2f((ushort_t)(v.x & 0xffffu)); r.y = b2f((ushort_t)(v.x >> 16));
  r.z = b2f((ushort_t)(v.y & 0xffffu)); r.w = b2f((ushort_t)(v.y >> 16));
  return r;
}

// ---------------- A generators: load4p(r, k, K) -> 4 packed bf16 ----------------
struct AgF32 { const float* A; int lda;
  __device__ uint2 load4p(int r, int k, int K) const {
    const float* p = &A[(size_t)r*lda + k];
    if (k+3 < K) { float4 v = *(const float4*)p; return pk4(v.x,v.y,v.z,v.w); }
    float a=0,b=0,c=0,d=0;
    if (k   < K) a = p[0];
    if (k+1 < K) b = p[1];
    if (k+2 < K) c = p[2];
    if (k+3 < K) d = p[3];
    return pk4(a,b,c,d); } };
struct AgBf16p { const ushort_t* A; int lda;
  __device__ uint2 load4p(int r, int k, int K) const {
    const ushort_t* p = &A[(size_t)r*lda + k];
    if (k+3 < K) return *(const uint2*)p;
    ushort_t a=0,b=0,c=0,d=0;
    if (k   < K) a = p[0];
    if (k+1 < K) b = p[1];
    if (k+2 < K) c = p[2];
    if (k+3 < K) d = p[3];
    uint2 q; q.x = (unsigned)a | ((unsigned)b<<16); q.y = (unsigned)c | ((unsigned)d<<16);
    return q; } };
struct AgStackA { const float* adj; const ushort_t* s2;   // rows<500: adj f32; >=500: S2 bf16
  __device__ uint2 load4p(int r, int k, int K) const {
    if (r < 500) {
      float a=0,b=0,c=0,d=0;
      const float* p = adj + (size_t)r*500 + k;
      if (k+3 < K) { float4 v = *(const float4*)p; return pk4(v.x,v.y,v.z,v.w); }
      if (k   < K) a = p[0];
      if (k+1 < K) b = p[1];
      if (k+2 < K) c = p[2];
      if (k+3 < K) d = p[3];
      return pk4(a,b,c,d);
    }
    const ushort_t* p = s2 + (size_t)(r-500)*500 + k;
    if (k+3 < K) return *(const uint2*)p;
    ushort_t a=0,b=0,c=0,d=0;
    if (k   < K) a = p[0];
    if (k+1 < K) b = p[1];
    if (k+2 < K) c = p[2];
    if (k+3 < K) d = p[3];
    uint2 q; q.x = (unsigned)a | ((unsigned)b<<16); q.y = (unsigned)c | ((unsigned)d<<16);
    return q; } };
struct AgXrow { const float* x;  // row=bt*500+n, k=c : x[bt,c,n]
  __device__ uint2 load4p(int r, int k, int K) const {
    int bt = r/500, n = r - bt*500;
    const float* p = x + (size_t)bt*32000 + n;
    float a=0,b=0,c=0,d=0;
    if (k   < K) a = p[(size_t)k*500];
    if (k+1 < K) b = p[(size_t)(k+1)*500];
    if (k+2 < K) c = p[(size_t)(k+2)*500];
    if (k+3 < K) d = p[(size_t)(k+3)*500];
    return pk4(a,b,c,d); } };
struct AgConvB { const ushort_t* hs; // bf16 hs; rows bn*24+t, k = dt*128+c
  __device__ uint2 load4p(int r, int k, int) const {
    int t = r % 24; int dt = k >> 7; int c = k & 127; int t2 = t + dt - 1;
    if (t2 < 0 || t2 >= 24) return z2();
    return *(const uint2*)&hs[(size_t)(r + (t2 - t))*128 + c]; } };
struct AgTeAdd { const float* o2f; const float* te;
  __device__ uint2 load4p(int r, int k, int) const {
    float4 a = *(const float4*)&o2f[(size_t)r*128 + k];
    float4 b = *(const float4*)&te[(size_t)(r/500)*128 + k];
    return pk4(a.x+b.x, a.y+b.y, a.z+b.z, a.w+b.w); } };

// ---------------- B generators: load4p(c, k, K) ----------------
struct BgPk { const ushort_t* B; int ldb;   // packed bf16 [N][K], k-contiguous
  __device__ uint2 load4p(int c, int k, int K) const {
    const ushort_t* p = &B[(size_t)c*ldb + k];
    if (k+3 < K) return *(const uint2*)p;
    ushort_t a=0,b=0,cc=0,d=0;
    if (k   < K) a = p[0];
    if (k+1 < K) b = p[1];
    if (k+2 < K) cc = p[2];
    if (k+3 < K) d = p[3];
    uint2 q; q.x = (unsigned)a | ((unsigned)b<<16); q.y = (unsigned)cc | ((unsigned)d<<16);
    return q; } };
struct BgXTv { const float* x;   // B[k][c]=x[c*500+k]
  __device__ uint2 load4p(int c, int k, int K) const {
    const float* p = x + (size_t)c*500 + k;
    if (k+3 < K) { float4 v = *(const float4*)p; return pk4(v.x,v.y,v.z,v.w); }
    float a=0,b=0,cc=0,d=0;
    if (k   < K) a = p[0];
    if (k+1 < K) b = p[1];
    if (k+2 < K) cc = p[2];
    if (k+3 < K) d = p[3];
    return pk4(a,b,cc,d); } };
struct BgAdjB { const float* adj;   // B[k][c]=adj[k*500+c]
  __device__ uint2 load4p(int c, int k, int K) const {
    float a=0,b=0,cc=0,d=0;
    if (k   < K) a = adj[(size_t)k*500 + c];
    if (k+1 < K) b = adj[(size_t)(k+1)*500 + c];
    if (k+2 < K) cc = adj[(size_t)(k+2)*500 + c];
    if (k+3 < K) d = adj[(size_t)(k+3)*500 + c];
    return pk4(a,b,cc,d); } };
struct BgY0T { const ushort_t* t;   // Y0T [128][192*500]; col c = bt*128+o
  __device__ uint2 load4p(int c, int k, int K) const {
    const ushort_t* p = &t[((size_t)(c & 127)*192 + (c >> 7))*500 + k];
    if (k+3 < K) return *(const uint2*)p;
    ushort_t a=0,b=0,cc=0,d=0;
    if (k   < K) a = p[0];
    if (k+1 < K) b = p[1];
    if (k+2 < K) cc = p[2];
    if (k+3 < K) d = p[3];
    uint2 qq; qq.x = (unsigned)a | ((unsigned)b<<16); qq.y = (unsigned)cc | ((unsigned)d<<16);
    return qq; } };

// ---------------- epilogues ----------------
struct EpNone { __device__ float operator()(int, int, float a) const { return a; } };
struct EpS2   { __device__ float operator()(int r, int c, float a) const { return 2.f*a - (r==c ? 1.f : 0.f); } };
struct EpBias { const float* b;
  __device__ float operator()(int, int c, float a) const { return a + b[c]; } };
struct EpRes1 { const ushort_t* out1; const float* st; const float *g, *bb, *rb; float invM;
  __device__ float operator()(int r, int c, float a) const {
    float mean = st[c]*invM; float var = st[128+c]*invM - mean*mean;
    float rstd = rsqrtf(var + 1e-5f);
    float y = (b2f(out1[(size_t)r*128 + c]) - mean)*rstd*g[c] + bb[c];
    y = fmaxf(y, 0.f);
    return a + rb[c] + y; } };
struct EpRes2 { const float *r2b, *rw, *rcb;
  __device__ float operator()(int, int c, float a) const {
    float s = 0.f;
    #pragma unroll
    for (int t=0; t<24; ++t) s += rw[t];
    return a + s*r2b[c] + rcb[0]; } };

// ---------------- pipelined MFMA generator GEMM ----------------
// OMODE: 0 = f32 store, 1 = bf16 store,
//        2 = xgT-transposed bf16 write (C=64 cols/bt), 3 = same with C=128.
template<int OMODE, class AG, class BG, class EP>
__global__ __launch_bounds__(256)
void gemm_mfma(AG ag, BG bg, EP ep, void* Cv, int M, int N, int K, int ldc) {
  constexpr int LDA = 40;
  __shared__ ushort_t As[128*LDA];
  __shared__ ushort_t Bs[128*LDA];
  int tid = threadIdx.x;
  int lane = tid & 63, wave = tid >> 6;
  int wr = (wave >> 1) * 64, wc = (wave & 1) * 64;
  int q = lane >> 4, r16 = lane & 15;
  int row0 = blockIdx.y*128, col0 = blockIdx.x*128;
  int am = tid >> 3, ak = (tid & 7) * 4;
  uint2 ua[4], ub[4];
  int nK = (K + 31) / 32;
  #pragma unroll
  for (int s=0;s<4;++s){
    int gr = row0 + am + 32*s;
    ua[s] = (gr < M) ? ag.load4p(gr, ak, K) : z2();
    int gc = col0 + am + 32*s;
    ub[s] = (gc < N) ? bg.load4p(gc, ak, K) : z2();
  }
  f32x4 acc[4][4] = {};
  for (int t=0; t<nK; ++t) {
    #pragma unroll
    for (int s=0;s<4;++s){
      *(uint2*)&As[(am + 32*s)*LDA + ak] = ua[s];
      *(uint2*)&Bs[(am + 32*s)*LDA + ak] = ub[s];
    }
    __syncthreads();
    if (t+1 < nK) {
      int k0 = (t+1)*32;
      #pragma unroll
      for (int s=0;s<4;++s){
        int gr = row0 + am + 32*s;
        ua[s] = (gr < M) ? ag.load4p(gr, k0+ak, K) : z2();
        int gc = col0 + am + 32*s;
        ub[s] = (gc < N) ? bg.load4p(gc, k0+ak, K) : z2();
      }
    }
    short8 a[4], b[4];
    #pragma unroll
    for (int it=0;it<4;++it) a[it] = *(const short8*)&As[(wr + it*16 + r16)*LDA + q*8];
    #pragma unroll
    for (int jt=0;jt<4;++jt) b[jt] = *(const short8*)&Bs[(wc + jt*16 + r16)*LDA + q*8];
    #pragma unroll
    for (int it=0;it<4;++it)
      #pragma unroll
      for (int jt=0;jt<4;++jt)
        acc[it][jt] = __builtin_amdgcn_mfma_f32_16x16x32_bf16(a[it], b[jt], acc[it][jt], 0, 0, 0);
    __syncthreads();
  }
  if constexpr (OMODE >= 2) {
    constexpr int CC = (OMODE == 2) ? 64 : 128;
    #pragma unroll
    for (int it=0;it<4;++it) {
      int rr0 = row0 + wr + it*16 + q*4;
      if (rr0 >= M) continue;
      int half = (rr0 >= 500) ? 1 : 0;
      int n0 = rr0 - half*500;
      #pragma unroll
      for (int jt=0;jt<4;++jt) {
        int c = col0 + wc + jt*16 + r16;
        if (c >= N) continue;
        int cin = c & (CC-1); int bt = c / CC;
        size_t addr = (size_t)(half*CC + cin)*96000 + (size_t)bt*500 + n0;
        *(uint2*)&((ushort_t*)Cv)[addr] =
            pk4(acc[it][jt][0], acc[it][jt][1], acc[it][jt][2], acc[it][jt][3]);
      }
    }
  } else {
    #pragma unroll
    for (int it=0;it<4;++it) {
      #pragma unroll
      for (int v=0;v<4;++v) {
        int rr = row0 + wr + it*16 + q*4 + v;
        if (rr >= M) continue;
        #pragma unroll
        for (int jt=0;jt<4;++jt) {
          int c = col0 + wc + jt*16 + r16;
          if (c >= N) continue;
          float val = ep(rr, c, acc[it][jt][v]);
          if (OMODE == 1) ((ushort_t*)Cv)[(size_t)rr*ldc + c] = f2b(val);
          else            ((float*)Cv)[(size_t)rr*ldc + c] = val;
        }
      }
    }
  }
}

// ---------------- LDS-free barrier-free flex GEMM ----------------
template<bool XSRC, bool BOUT>
__global__ __launch_bounds__(256, 3)
void k_flex(const float* x, const ushort_t* xgT, const ushort_t* wpf,
            const float* ne, const float* bp, void* Cv, int nKC) {
  int tid = threadIdx.x;
  int lane = tid & 63, wave = tid >> 6;
  int wr = (wave >> 1) * 64, wc = (wave & 1) * 64;
  int q = lane >> 4, r16 = lane & 15;
  int row0 = blockIdx.x * 128;
  int rowIt[4]; size_t xoff[4];
  float ne8[4][8];
  #pragma unroll
  for (int it=0; it<4; ++it) {
    int r = row0 + wr + it*16 + r16;
    rowIt[it] = r;
    if (XSRC) { int bt = r/500; int n = r - bt*500; xoff[it] = (size_t)bt*32000 + n; }
    float4 p0 = *(const float4*)&ne[(size_t)r*8];
    float4 p1 = *(const float4*)&ne[(size_t)r*8 + 4];
    ne8[it][0]=p0.x; ne8[it][1]=p0.y; ne8[it][2]=p0.z; ne8[it][3]=p0.w;
    ne8[it][4]=p1.x; ne8[it][5]=p1.y; ne8[it][6]=p1.z; ne8[it][7]=p1.w;
  }
  int cB = wc + r16;
  f32x4 acc[4][4] = {};
  int nT = nKC >> 2;
  float vc[4]; uint4 bc[4];
  {
    int kc = q;
    #pragma unroll
    for (int jt=0;jt<4;++jt)
      bc[jt] = *(const uint4*)&wpf[((size_t)kc*128 + cB + jt*16)*8];
    #pragma unroll
    for (int it=0;it<4;++it) {
      if (XSRC) vc[it] = x[xoff[it] + (size_t)kc*500];
      else      vc[it] = b2f(xgT[(size_t)kc*96000 + rowIt[it]]);
    }
  }
  for (int t=0; t<nT; ++t) {
    float vn[4]; uint4 bnx[4];
    if (t+1 < nT) {
      int kc = (t+1)*4 + q;
      #pragma unroll
      for (int jt=0;jt<4;++jt)
        bnx[jt] = *(const uint4*)&wpf[((size_t)kc*128 + cB + jt*16)*8];
      bool fromX = XSRC && (kc < 64);
      if (fromX) {
        #pragma unroll
        for (int it=0;it<4;++it) vn[it] = x[xoff[it] + (size_t)kc*500];
      } else {
        int kcx = XSRC ? (kc - 64) : kc;
        #pragma unroll
        for (int it=0;it<4;++it) vn[it] = b2f(xgT[(size_t)kcx*96000 + rowIt[it]]);
      }
    } else {
      #pragma unroll
      for (int it=0;it<4;++it) vn[it] = 0.f;
      #pragma unroll
      for (int jt=0;jt<4;++jt) { bnx[jt].x=0u; bnx[jt].y=0u; bnx[jt].z=0u; bnx[jt].w=0u; }
    }
    short8 a[4], b[4];
    #pragma unroll
    for (int jt=0;jt<4;++jt) b[jt] = __builtin_bit_cast(short8, bc[jt]);
    #pragma unroll
    for (int it=0;it<4;++it) {
      float v = vc[it];
      uint4 pw;
      pw.x = cvtpk(v*ne8[it][0], v*ne8[it][1]);
      pw.y = cvtpk(v*ne8[it][2], v*ne8[it][3]);
      pw.z = cvtpk(v*ne8[it][4], v*ne8[it][5]);
      pw.w = cvtpk(v*ne8[it][6], v*ne8[it][7]);
      a[it] = __builtin_bit_cast(short8, pw);
    }
    #pragma unroll
    for (int it=0;it<4;++it)
      #pragma unroll
      for (int jt=0;jt<4;++jt)
        acc[it][jt] = __builtin_amdgcn_mfma_f32_16x16x32_bf16(a[it], b[jt], acc[it][jt], 0, 0, 0);
    #pragma unroll
    for (int it=0;it<4;++it) vc[it] = vn[it];
    #pragma unroll
    for (int jt=0;jt<4;++jt) bc[jt] = bnx[jt];
  }
  #pragma unroll
  for (int it=0;it<4;++it) {
    #pragma unroll
    for (int v=0;v<4;++v) {
      int rr = row0 + wr + it*16 + q*4 + v;
      #pragma unroll
      for (int jt=0;jt<4;++jt) {
        int c = wc + jt*16 + r16;
        float val = acc[it][jt][v];
        #pragma unroll
        for (int d=0; d<8; ++d) val += ne[(size_t)rr*8 + d]*bp[d*128 + c];
        if (BOUT) ((ushort_t*)Cv)[(size_t)rr*128 + c] = f2b(val);
        else      ((float*)Cv)[(size_t)rr*128 + c] = val;
      }
    }
  }
}

// ---------------- packing kernels ----------------
__global__ void k_pack_bf(const float* s, ushort_t* d, int n){
  int i = blockIdx.x*256 + threadIdx.x; if (i < n) d[i] = f2b(s[i]); }
// fragment-order pack: d[(kc*128+c)*8+e] = wp[d=e][kk][cin][c], kk=kc/C cin=kc%C
__global__ void k_pack_wpf(const float* wp, ushort_t* d, int C, int KC){
  int i = blockIdx.x*256 + threadIdx.x; int total = KC*128*8; if (i >= total) return;
  int e = i & 7; int rest = i >> 3; int c = rest & 127; int kc = rest >> 7;
  int kk = kc / C; int cin = kc - kk*C;
  d[i] = f2b(wp[(((size_t)e*3 + kk)*C + cin)*128 + c]); }
__global__ void k_pack_qkvw(const float* cqw, const float* ckw, const float* vw, ushort_t* d){
  int i = blockIdx.x*256 + threadIdx.x; if (i >= 147456) return;
  int o = i / 384; int r = i - o*384; int dt = r >> 7; int cin = r & 127;
  float v;
  if (o < 128) v = cqw[((size_t)o*128 + cin)*3 + dt];
  else if (o < 256) v = ckw[((size_t)(o-128)*128 + cin)*3 + dt];
  else v = (dt==1) ? vw[(size_t)(o-256)*128 + cin] : 0.f;
  d[i] = f2b(v); }
__global__ void k_pack_qkvb(const float* cqb, const float* ckb, const float* vb, float* d){
  int i = threadIdx.x; // 384
  d[i] = (i<128) ? cqb[i] : (i<256) ? ckb[i-128] : vb[i-256]; }

// ---------------- small kernels ----------------
// Fused Phase-B: read RAW out0, apply BN0+relu, write Y0T [o][bt][n] (= xgT1 rows 0..127)
// and pooled partial sums (atomic).
__global__ void k_fuseB(const float* out0, const float* st, const float* g, const float* b,
                        ushort_t* y0t, float* pooled) {
  __shared__ float tile[32][33];
  __shared__ float red[8][32];
  int bt = blockIdx.z; int n0 = blockIdx.x*32; int o0 = blockIdx.y*32;
  int tx = threadIdx.x, ty = threadIdx.y;  // 32x8
  int o = o0 + tx;
  float mean = st[o]*(1.f/96000.f);
  float var  = st[128+o]*(1.f/96000.f) - mean*mean;
  float sc = rsqrtf(var + 1e-5f)*g[o];
  float bb = b[o] - mean*sc;
  float psum = 0.f;
  for (int i = ty; i < 32; i += 8) {
    int n = n0 + i;
    float y = 0.f;
    if (n < 500) {
      float v = out0[((size_t)bt*500 + n)*128 + o];
      y = fmaxf(v*sc + bb, 0.f);
      psum += y;
    }
    tile[i][tx] = y;
  }
  red[ty][tx] = psum;
  __syncthreads();
  if (ty == 0) {
    float s = red[0][tx];
    #pragma unroll
    for (int k=1;k<8;++k) s += red[k][tx];
    atomicAdd(&pooled[bt*128 + o], s*(1.f/500.f));
  }
  for (int i = ty; i < 32; i += 8) {
    int oo = o0 + i; int n = n0 + tx;
    if (n < 500) y0t[(size_t)oo*96000 + (size_t)bt*500 + n] = f2b(tile[tx][i]);
  }
}

__global__ void k_pool0(const float* x, float* pooled) {
  int bt = blockIdx.x; int c = threadIdx.x;
  const float* p = x + (size_t)bt*32000 + (size_t)c*500;
  float s = 0.f;
  for (int n=0;n<500;++n) s += p[n];
  pooled[bt*64 + c] = s*(1.f/500.f);
}

// parallel 2-layer MLP + softmax: 1 block per bt, 128 threads, wave-shuffle reduce.
__global__ __launch_bounds__(128) void k_mlp_p(const float* pooled, int F,
                      const float* f1w, const float* f1b,
                      const float* f2w, const float* f2b, float* aout) {
  int bt = blockIdx.x; int c = threadIdx.x;   // 128 threads = 2 waves
  __shared__ float red2[2][8];
  __shared__ float hsh[8];
  float p = (c < F) ? pooled[bt*F + c] : 0.f;
  #pragma unroll
  for (int k=0;k<8;++k){
    float v = (c < F) ? p*f1w[k*F + c] : 0.f;
    #pragma unroll
    for (int off=32; off>0; off>>=1) v += __shfl_down(v, off);
    if ((c & 63) == 0) red2[c>>6][k] = v;
  }
  __syncthreads();
  if (c < 8) {
    float s = red2[0][c] + red2[1][c] + f1b[c];
    hsh[c] = fmaxf(s, 0.f);
  }
  __syncthreads();
  if (c == 0) {
    float z[8]; float m = -1e30f;
    #pragma unroll
    for (int k2=0;k2<8;++k2){
      float s = f2b[k2];
      #pragma unroll
      for (int k=0;k<8;++k) s += hsh[k]*f2w[k2*8 + k];
      z[k2] = s; m = fmaxf(m, s);
    }
    float den = 0.f;
    #pragma unroll
    for (int k2=0;k2<8;++k2){ z[k2] = __expf(z[k2]-m); den += z[k2]; }
    float inv = 1.f/den;
    #pragma unroll
    for (int k2=0;k2<8;++k2) aout[bt*8 + k2] = z[k2]*inv;
  }
}

__global__ void k_ne(const float* a, const float* emb, float* ne) {
  int i = blockIdx.x*256 + threadIdx.x;
  if (i >= 768000) return;
  int d = i & 7; int rem = i >> 3; int n = rem % 500; int bt = rem / 500;
  float s = 0.f;
  #pragma unroll
  for (int k=0;k<8;++k) s += a[bt*8 + k]*emb[((size_t)k*500 + n)*8 + d];
  ne[i] = s;
}

__global__ void k_bn_stats(const float* src, float* stats, int M, int rpb) {
  int col = threadIdx.x & 127; int seg = threadIdx.x >> 7;
  int r0 = blockIdx.x * rpb; int r1 = r0 + rpb; if (r1 > M) r1 = M;
  float s = 0.f, q = 0.f;
  for (int r = r0 + seg; r < r1; r += 2) {
    float v = src[(size_t)r*128 + col];
    s += v; q += v*v;
  }
  atomicAdd(&stats[col], s);
  atomicAdd(&stats[128+col], q);
}
__global__ void k_bn_stats_bf(const ushort_t* src, float* stats, int M, int rpb) {
  int col = threadIdx.x & 127; int seg = threadIdx.x >> 7;
  int r0 = blockIdx.x * rpb; int r1 = r0 + rpb; if (r1 > M) r1 = M;
  float s = 0.f, q = 0.f;
  for (int r = r0 + seg; r < r1; r += 2) {
    float v = b2f(src[(size_t)r*128 + col]);
    s += v; q += v*v;
  }
  atomicAdd(&stats[col], s);
  atomicAdd(&stats[128+col], q);
}

__global__ void k_bn_apply4(float* dst, const float* src, const float* st,
                            const float* g, const float* b, int total4, float invM, int relu, int addd) {
  int i = blockIdx.x*256 + threadIdx.x;
  if (i >= total4) return;
  int i4 = i*4; int c = i4 & 127;
  float4 sm = *(const float4*)&st[c];
  float4 sq = *(const float4*)&st[128+c];
  float4 g4 = *(const float4*)&g[c];
  float4 b4 = *(const float4*)&b[c];
  float4 v = *(const float4*)&src[i4];
  float4 y;
  {
    float mean = sm.x*invM; float var = sq.x*invM - mean*mean;
    y.x = (v.x-mean)*rsqrtf(var+1e-5f)*g4.x + b4.x;
    mean = sm.y*invM; var = sq.y*invM - mean*mean;
    y.y = (v.y-mean)*rsqrtf(var+1e-5f)*g4.y + b4.y;
    mean = sm.z*invM; var = sq.z*invM - mean*mean;
    y.z = (v.z-mean)*rsqrtf(var+1e-5f)*g4.z + b4.z;
    mean = sm.w*invM; var = sq.w*invM - mean*mean;
    y.w = (v.w-mean)*rsqrtf(var+1e-5f)*g4.w + b4.w;
  }
  if (relu){ y.x=fmaxf(y.x,0.f); y.y=fmaxf(y.y,0.f); y.z=fmaxf(y.z,0.f); y.w=fmaxf(y.w,0.f); }
  if (addd){ float4 d0 = *(const float4*)&dst[i4]; y.x+=d0.x; y.y+=d0.y; y.z+=d0.z; y.w+=d0.w; }
  *(float4*)&dst[i4] = y;
}

// in-place BN apply + relu on bf16 buffer
__global__ void k_bn_apply_bf_ip(ushort_t* buf, const float* st,
                                 const float* g, const float* b, int total4, float invM) {
  int i = blockIdx.x*256 + threadIdx.x;
  if (i >= total4) return;
  int i4 = i*4; int c = i4 & 127;
  uint2 vv = *(const uint2*)&buf[i4];
  float v0 = b2f((ushort_t)(vv.x & 0xffffu)), v1 = b2f((ushort_t)(vv.x >> 16));
  float v2 = b2f((ushort_t)(vv.y & 0xffffu)), v3 = b2f((ushort_t)(vv.y >> 16));
  float4 sm = *(const float4*)&st[c];
  float4 sq = *(const float4*)&st[128+c];
  float4 g4 = *(const float4*)&g[c];
  float4 b4 = *(const float4*)&b[c];
  float mean, var, y0, y1, y2, y3;
  mean = sm.x*invM; var = sq.x*invM - mean*mean;
  y0 = (v0-mean)*rsqrtf(var+1e-5f)*g4.x + b4.x;
  mean = sm.y*invM; var = sq.y*invM - mean*mean;
  y1 = (v1-mean)*rsqrtf(var+1e-5f)*g4.y + b4.y;
  mean = sm.z*invM; var = sq.z*invM - mean*mean;
  y2 = (v2-mean)*rsqrtf(var+1e-5f)*g4.z + b4.z;
  mean = sm.w*invM; var = sq.w*invM - mean*mean;
  y3 = (v3-mean)*rsqrtf(var+1e-5f)*g4.w + b4.w;
  y0=fmaxf(y0,0.f); y1=fmaxf(y1,0.f); y2=fmaxf(y2,0.f); y3=fmaxf(y3,0.f);
  *(uint2*)&buf[i4] = pk4(y0,y1,y2,y3);
}

// ---------------- MFMA recurrent GRU (+fused stats, bf16 hs out) ----------------
__global__ __launch_bounds__(256, 1) void k_gru_mfma(
    const ushort_t* gi, const ushort_t* whhp, const float* bhh,
    ushort_t* hsb, float* stats) {
  __shared__ ushort_t hbf[16*128];   // bf16 h, 16B-chunk XOR swizzled
  __shared__ float    uh[16*384];    // f32 uh, swizzled; reused as stats scratch

  int tid  = threadIdx.x;
  int lane = tid & 63;
  int wave = tid >> 6;
  int r16  = lane & 15, q = lane >> 4;

  short8 bfrag[6][4];
  #pragma unroll
  for (int j=0;j<6;++j){
    int col = (wave*6 + j)*16 + r16;
    #pragma unroll
    for (int kk=0;kk<4;++kk)
      bfrag[j][kk] = *(const short8*)&whhp[(size_t)col*128 + kk*32 + q*8];
  }

  int gr = tid >> 4;           // 0..15
  int gc = tid & 15;           // chunk index
  int u0 = gc*8;
  int s  = blockIdx.x*16 + gr;
  int b  = s / 500, n = s - b*500;
  size_t gi_base = ((size_t)b*24*500 + n)*384;   // + t*192000
  size_t hs_base = (size_t)s*24*128 + u0;        // + t*128 (bf16)

  float bh0[8], bh1[8], bh2[8];
  #pragma unroll
  for (int k=0;k<8;++k){ bh0[k]=bhh[u0+k]; bh1[k]=bhh[128+u0+k]; bh2[k]=bhh[256+u0+k]; }

  float h[8], sacc[8], qacc[8];
  #pragma unroll
  for (int k=0;k<8;++k){ h[k]=0.f; sacc[k]=0.f; qacc[k]=0.f; }
  {
    int phys = gr*128 + ((gc ^ (gr&7))*8);
    uint4 zz; zz.x=0u; zz.y=0u; zz.z=0u; zz.w=0u;
    *(uint4*)&hbf[phys] = zz;
  }

  for (int t=0;t<24;++t){
    __syncthreads();
    const ushort_t* gp = gi + gi_base + (size_t)t*192000;
    uint4 gir = *(const uint4*)&gp[u0];
    uint4 giz = *(const uint4*)&gp[128+u0];
    uint4 gin = *(const uint4*)&gp[256+u0];

    short8 afrag[4];
    #pragma unroll
    for (int kk=0;kk<4;++kk)
      afrag[kk] = *(const short8*)&hbf[r16*128 + (((kk<<2)+q) ^ (r16&7))*8];
    #pragma unroll
    for (int j=0;j<6;++j){
      f32x4 acc = {};
      #pragma unroll
      for (int kk=0;kk<4;++kk)
        acc = __builtin_amdgcn_mfma_f32_16x16x32_bf16(afrag[kk], bfrag[j][kk], acc, 0, 0, 0);
      int col = (wave*6+j)*16 + r16;
      #pragma unroll
      for (int v=0;v<4;++v){
        int rr = q*4 + v;
        uh[rr*384 + ((((col>>2) ^ (rr&7))<<2) | (col&3))] = acc[v];
      }
    }
    __syncthreads();

    float hr[8], hz[8], hn[8];
    {
      int rw = gr*384; int sw = gr & 7;
      int c0 = (u0>>2);
      float4 A, Bv;
      A  = *(const float4*)&uh[rw + ((c0      ^ sw)<<2)];
      Bv = *(const float4*)&uh[rw + (((c0+1)  ^ sw)<<2)];
      hr[0]=A.x; hr[1]=A.y; hr[2]=A.z; hr[3]=A.w; hr[4]=Bv.x; hr[5]=Bv.y; hr[6]=Bv.z; hr[7]=Bv.w;
      int c1 = ((128+u0)>>2);
      A  = *(const float4*)&uh[rw + ((c1      ^ sw)<<2)];
      Bv = *(const float4*)&uh[rw + (((c1+1)  ^ sw)<<2)];
      hz[0]=A.x; hz[1]=A.y; hz[2]=A.z; hz[3]=A.w; hz[4]=Bv.x; hz[5]=Bv.y; hz[6]=Bv.z; hz[7]=Bv.w;
      int c2 = ((256+u0)>>2);
      A  = *(const float4*)&uh[rw + ((c2      ^ sw)<<2)];
      Bv = *(const float4*)&uh[rw + (((c2+1)  ^ sw)<<2)];
      hn[0]=A.x; hn[1]=A.y; hn[2]=A.z; hn[3]=A.w; hn[4]=Bv.x; hn[5]=Bv.y; hn[6]=Bv.z; hn[7]=Bv.w;
    }
    float ir[8], iz[8], in_[8];
    unp8(gir, ir); unp8(giz, iz); unp8(gin, in_);
    #pragma unroll
    for (int k=0;k<8;++k){
      float rg = fsig(ir[k] + hr[k] + bh0[k]);
      float zg = fsig(iz[k] + hz[k] + bh1[k]);
      float ng = ftanh(in_[k] + rg*(hn[k] + bh2[k]));
      float hv = (1.f - zg)*ng + zg*h[k];
      h[k] = hv;
      sacc[k] += hv; qacc[k] += hv*hv;
    }
    uint2 p0 = pk4(h[0],h[1],h[2],h[3]);
    uint2 p1 = pk4(h[4],h[5],h[6],h[7]);
    uint4 pw; pw.x=p0.x; pw.y=p0.y; pw.z=p1.x; pw.w=p1.y;
    {
      int phys = gr*128 + ((gc ^ (gr&7))*8);
      *(uint4*)&hbf[phys] = pw;
    }
    *(uint4*)&hsb[hs_base + (size_t)t*128] = pw;
  }

  __syncthreads();
  #pragma unroll
  for (int k=0;k<8;++k) uh[gr*128 + u0 + k] = sacc[k];
  __syncthreads();
  if (tid < 128) {
    float ss = 0.f;
    for (int r=0;r<16;++r) ss += uh[r*128 + tid];
    atomicAdd(&stats[tid], ss);
  }
  __syncthreads();
  #pragma unroll
  for (int k=0;k<8;++k) uh[gr*128 + u0 + k] = qacc[k];
  __syncthreads();
  if (tid < 128) {
    float qq = 0.f;
    for (int r=0;r<16;++r) qq += uh[r*128 + tid];
    atomicAdd(&stats[128 + tid], qq);
  }
}

// attention over interleaved QKV [r][384] — bank-aligned pitch 128 + 16B-chunk XOR.
// Store elem (t,c) at A[t*128 + ((c>>2)^(t&7))*4 + (c&3)].
__global__ __launch_bounds__(256) void k_attn3(const ushort_t* QKV,
    const float* ow, const float* ob, const float* fcw, const float* fcb, float* out2f) {
  __shared__ float A1[24*128];
  __shared__ float A2[24*128];
  __shared__ float Sc[8][24][25];
  __shared__ float red[256];
  int bn = blockIdx.x; int tid = threadIdx.x;
  size_t base = (size_t)bn*9216;   // 24*384
  // load Q,K (vectorized: 4 elems/thread)
  for (int i=tid;i<768;i+=256){
    int t=i>>5, c4=i&31;
    uint2 q2 = *(const uint2*)&QKV[base + (size_t)t*384 + c4*4];
    uint2 k2 = *(const uint2*)&QKV[base + (size_t)t*384 + 128 + c4*4];
    int phys = t*128 + ((c4^(t&7))<<2);
    *(float4*)&A1[phys] = unpk4f(q2);
    *(float4*)&A2[phys] = unpk4f(k2);
  }
  __syncthreads();
  // QK^T
  for (int i=tid;i<4608;i+=256){
    int hh = i/576; int r = i - hh*576; int t = r/24; int s_ = r - t*24;
    float d0 = 0.f, d1 = 0.f;
    #pragma unroll
    for (int dd4=0;dd4<4;++dd4){
      float4 qv = *(const float4*)&A1[t*128 + ((((hh<<2)+dd4)^(t&7))<<2)];
      float4 kv = *(const float4*)&A2[s_*128 + ((((hh<<2)+dd4)^(s_&7))<<2)];
      d0 += qv.x*kv.x + qv.y*kv.y;
      d1 += qv.z*kv.z + qv.w*kv.w;
    }
    Sc[hh][t][s_] = (d0+d1)*0.25f;
  }
  __syncthreads();
  // load V into A2 (vectorized)
  for (int i=tid;i<768;i+=256){
    int t=i>>5, c4=i&31;
    uint2 v2 = *(const uint2*)&QKV[base + (size_t)t*384 + 256 + c4*4];
    *(float4*)&A2[t*128 + ((c4^(t&7))<<2)] = unpk4f(v2);
  }
  if (tid < 192) {
    int hh = tid/24, t = tid - (tid/24)*24;
    float m = -1e30f;
    for (int s_=0;s_<24;++s_) m = fmaxf(m, Sc[hh][t][s_]);
    float den = 0.f;
    for (int s_=0;s_<24;++s_){ float e = __expf(Sc[hh][t][s_]-m); Sc[hh][t][s_] = e; den += e; }
    float inv = 1.f/den;
    for (int s_=0;s_<24;++s_) Sc[hh][t][s_] *= inv;
  }
  __syncthreads();
  // PV (vectorized over o: 4 outputs/thread)
  for (int i=tid;i<768;i+=256){
    int t = i>>5; int o4 = i&31; int hh = o4>>2;
    float4 s = {0.f,0.f,0.f,0.f};
    #pragma unroll
    for (int s_=0;s_<24;++s_){
      float p = Sc[hh][t][s_];
      float4 v = *(const float4*)&A2[s_*128 + ((o4^(s_&7))<<2)];
      s.x += p*v.x; s.y += p*v.y; s.z += p*v.z; s.w += p*v.w;
    }
    *(float4*)&A1[t*128 + ((o4^(t&7))<<2)] = s;
  }
  __syncthreads();
  // xbar: 256-thread split reduction over t
  int o = tid & 127, hf = tid >> 7;
  {
    float s = 0.f;
    for (int t = hf*12; t < hf*12 + 12; ++t)
      s += fcw[t]*A1[t*128 + ((((o>>2)^(t&7))<<2) | (o&3))];
    red[tid] = s;
  }
  __syncthreads();
  float* xbar = &Sc[0][0][0];
  if (tid < 128) xbar[tid] = red[tid] + red[tid+128];
  __syncthreads();
  // ow: 256-thread split reduction over c
  {
    float s = 0.f;
    for (int c = hf*64; c < hf*64 + 64; ++c) s += xbar[c]*ow[o*128 + c];
    red[tid] = s;
  }
  __syncthreads();
  if (tid < 128) {
    float sfc = 0.f;
    for (int t=0;t<24;++t) sfc += fcw[t];
    out2f[(size_t)bn*128 + o] = red[tid] + red[tid+128] + sfc*ob[o] + fcb[0];
  }
}

__global__ void k_rbar_bf(const ushort_t* out2, const float* rw, float* rbar) {
  int i = blockIdx.x*256 + threadIdx.x;
  if (i >= 512000) return;
  int c = i & 127; int bnn = i >> 7; int b = bnn/500, n = bnn - b*500;
  float s = 0.f;
  #pragma unroll
  for (int t=0;t<24;++t) s += rw[t] * b2f(out2[((size_t)(b*24 + t)*500 + n)*128 + c]);
  rbar[i] = s;
}

__global__ void k_te(const float* tt, const float* w1, const float* b1,
                     const float* w2, const float* b2, float* te) {
  __shared__ float h1[128];
  int b = blockIdx.x; int o = threadIdx.x;
  float s = b1[o];
  for (int c=0;c<32;++c) s += tt[b*32 + c]*w1[o*32 + c];
  h1[o] = fmaxf(s, 0.f);
  __syncthreads();
  float s2 = b2[o];
  for (int c=0;c<128;++c) s2 += h1[c]*w2[o*128 + c];
  te[b*128 + o] = s2;
}

__global__ void k_grid(const float* gnm, const float* fin, float* out) {
  int e = threadIdx.x & 63; int gq = threadIdx.x >> 6;
  int g = blockIdx.x*4 + gq; int b = blockIdx.y;
  float s = 0.f;
  const float* gr = gnm + (size_t)g*500;
  const float* fb = fin + (size_t)b*500*64 + e;
  for (int n=0;n<500;++n) s += gr[n] * fb[(size_t)n*64];
  out[(size_t)b*32000 + (size_t)e*500 + g] = s;
}

// ---------------- launch ----------------
extern "C" void kernel_launch(void* const* d_in, const int* in_sizes, int n_in,
                              void* d_out, int out_size, void* d_ws, size_t ws_size,
                              hipStream_t stream) {
  const float* adj   = (const float*)d_in[0];
  const float* x     = (const float*)d_in[1];
  const float* gnm   = (const float*)d_in[2];
  const float* ttime = (const float*)d_in[3];
  const float* emb   = (const float*)d_in[4];
  const float* wp0   = (const float*)d_in[5];
  const float* bp0   = (const float*)d_in[6];
  const float* a0f1w = (const float*)d_in[7];
  const float* a0f1b = (const float*)d_in[8];
  const float* a0f2w = (const float*)d_in[9];
  const float* a0f2b = (const float*)d_in[10];
  const float* wp1   = (const float*)d_in[11];
  const float* bp1   = (const float*)d_in[12];
  const float* a1f1w = (const float*)d_in[13];
  const float* a1f1b = (const float*)d_in[14];
  const float* a1f2w = (const float*)d_in[15];
  const float* a1f2b = (const float*)d_in[16];
  const float* bn0g  = (const float*)d_in[17];
  const float* bn0b  = (const float*)d_in[18];
  const float* bn1g  = (const float*)d_in[19];
  const float* bn1b  = (const float*)d_in[20];
  const float* wih   = (const float*)d_in[21];
  const float* whh   = (const float*)d_in[22];
  const float* bih   = (const float*)d_in[23];
  const float* bhh   = (const float*)d_in[24];
  const float* bgg   = (const float*)d_in[25];
  const float* bgb   = (const float*)d_in[26];
  const float* cqw   = (const float*)d_in[27];
  const float* cqb   = (const float*)d_in[28];
  const float* ckw   = (const float*)d_in[29];
  const float* ckb   = (const float*)d_in[30];
  const float* vw    = (const float*)d_in[31];
  const float* vb    = (const float*)d_in[32];
  const float* ow    = (const float*)d_in[33];
  const float* ob    = (const float*)d_in[34];
  const float* r1w   = (const float*)d_in[35];
  const float* r1b   = (const float*)d_in[36];
  const float* fcw   = (const float*)d_in[37];
  const float* fcb   = (const float*)d_in[38];
  const float* rcw   = (const float*)d_in[39];
  const float* rcb   = (const float*)d_in[40];
  const float* r2w   = (const float*)d_in[41];
  const float* r2b   = (const float*)d_in[42];
  const float* bnrg  = (const float*)d_in[43];
  const float* bnrb  = (const float*)d_in[44];
  const float* te1w  = (const float*)d_in[45];
  const float* te1b  = (const float*)d_in[46];
  const float* te2w  = (const float*)d_in[47];
  const float* te2b  = (const float*)d_in[48];
  const float* finw  = (const float*)d_in[49];
  const float* finb  = (const float*)d_in[50];
  float* dout = (float*)d_out;
  float* W = (float*)d_ws;

  size_t off = 0;
  auto alloc = [&](size_t n){ size_t r = off; off += (n + 255) & ~(size_t)255; return r; };
  size_t oStats = alloc(512);
  size_t oPool  = alloc(24576);
  size_t oAmix  = alloc(1536);
  size_t oTe    = alloc(1024);
  size_t oO2f   = alloc(512000);
  size_t oRbar  = alloc(512000);
  size_t oRes   = alloc(512000);
  size_t oFin   = alloc(256000);
  size_t oNe0   = alloc(768000);
  size_t oNe1   = alloc(768000);
  size_t oS2    = alloc(125000);     // bf16 [500][500]
  size_t oWpf0  = alloc(98304);      // bf16 [192][128][8]
  size_t oWpf1  = alloc(196608);     // bf16 [384][128][8]
  size_t oR1wp  = alloc(4096);       // bf16 [128][64]
  size_t oWihp  = alloc(24576);      // bf16 [384][128]
  size_t oWhhp  = alloc(24576);      // bf16 [384][128]
  size_t oQkvw  = alloc(73728);      // bf16 [384][384]
  size_t oQkvb  = alloc(384);
  size_t oR2wp  = alloc(8192);
  size_t oFinwp = alloc(4096);
  size_t oR1    = alloc(12288000);   // out0 (f32) -> out2b (bf16)
  size_t oR2    = alloc(12288000);   // xgT1 low -> gi(low) -> QKV(low)
  size_t oR4    = alloc(6144000);    // xgT0 -> xgT1 high -> gi(high) -> QKV(high)
  size_t oOut1  = alloc(6144000);    // out1 -> hsb (bf16, in-place BN)
  (void)n_in; (void)in_sizes; (void)out_size;
  if (ws_size < off * sizeof(float)) return;

  float* stats = W + oStats;
  float* pooled= W + oPool;
  float* amix  = W + oAmix;
  float* teb   = W + oTe;
  float* out2f = W + oO2f;
  float* rbar  = W + oRbar;
  float* resout= W + oRes;
  float* fin   = W + oFin;
  float* ne0   = W + oNe0;
  float* ne1   = W + oNe1;
  ushort_t* S2bf  = (ushort_t*)(W + oS2);
  ushort_t* wpf0  = (ushort_t*)(W + oWpf0);
  ushort_t* wpf1  = (ushort_t*)(W + oWpf1);
  ushort_t* r1wp  = (ushort_t*)(W + oR1wp);
  ushort_t* wihp  = (ushort_t*)(W + oWihp);
  ushort_t* whhp  = (ushort_t*)(W + oWhhp);
  ushort_t* qkvwp = (ushort_t*)(W + oQkvw);
  float*    qkvb  = W + oQkvb;
  ushort_t* r2wp  = (ushort_t*)(W + oR2wp);
  ushort_t* finwp = (ushort_t*)(W + oFinwp);
  float* out0  = W + oR1;
  ushort_t* out2b = (ushort_t*)(W + oR1);    // after out0 dead
  ushort_t* xgT1 = (ushort_t*)(W + oR2);     // [384][96000] spans R2+R4 (contiguous)
  ushort_t* gi16 = (ushort_t*)(W + oR2);     // [96000][384] spans R2+R4
  ushort_t* qkv16= (ushort_t*)(W + oR2);     // same span (gi dead)
  ushort_t* xgT0 = (ushort_t*)(W + oR4);     // [128][96000] during phase A
  ushort_t* out1 = (ushort_t*)(W + oOut1);
  ushort_t* hsb  = (ushort_t*)(W + oOut1);   // after out1 dead

  // ---- weight packing ----
  k_pack_wpf<<<768, 256, 0, stream>>>(wp0, wpf0, 64, 192);
  k_pack_wpf<<<1536, 256, 0, stream>>>(wp1, wpf1, 128, 384);
  k_pack_bf<<<32, 256, 0, stream>>>(r1w, r1wp, 8192);
  k_pack_bf<<<192, 256, 0, stream>>>(wih, wihp, 49152);
  k_pack_bf<<<192, 256, 0, stream>>>(whh, whhp, 49152);
  k_pack_bf<<<64, 256, 0, stream>>>(r2w, r2wp, 16384);
  k_pack_bf<<<32, 256, 0, stream>>>(finw, finwp, 8192);
  k_pack_qkvw<<<576, 256, 0, stream>>>(cqw, ckw, vw, qkvwp);
  k_pack_qkvb<<<1, 384, 0, stream>>>(cqb, ckb, vb, qkvb);

  // ---- Phase A ----
  gemm_mfma<1><<<dim3(4,4), 256, 0, stream>>>(
      AgF32{adj,500}, BgAdjB{adj}, EpS2{}, (void*)S2bf, 500, 500, 500, 500);
  gemm_mfma<2><<<dim3(96,8), 256, 0, stream>>>(
      AgStackA{adj, S2bf}, BgXTv{x}, EpNone{}, (void*)xgT0, 1000, 12288, 500, 0);
  k_pool0<<<192, 64, 0, stream>>>(x, pooled);
  k_mlp_p<<<192, 128, 0, stream>>>(pooled, 64, a0f1w, a0f1b, a0f2w, a0f2b, amix);
  k_ne<<<3000, 256, 0, stream>>>(amix, emb, ne0);
  k_flex<true, false><<<750, 256, 0, stream>>>(
      x, xgT0, wpf0, ne0, bp0, (void*)out0, 192);
  hipMemsetAsync((void*)stats, 0, 256*sizeof(float), stream);
  k_bn_stats<<<768, 256, 0, stream>>>(out0, stats, 96000, 125);

  // ---- Phase B (fused BN0+relu -> Y0T(=xgT1 rows 0..127) + pooled) ----
  hipMemsetAsync((void*)pooled, 0, 24576*sizeof(float), stream);
  k_fuseB<<<dim3(16,4,192), dim3(32,8), 0, stream>>>(out0, stats, bn0g, bn0b, xgT1, pooled);
  k_mlp_p<<<192, 128, 0, stream>>>(pooled, 128, a1f1w, a1f1b, a1f2w, a1f2b, amix);
  k_ne<<<3000, 256, 0, stream>>>(amix, emb, ne1);
  gemm_mfma<3><<<dim3(192,8), 256, 0, stream>>>(
      AgStackA{adj, S2bf}, BgY0T{xgT1}, EpNone{},
      (void*)(xgT1 + (size_t)128*96000), 1000, 24576, 500, 0);
  k_flex<false, true><<<750, 256, 0, stream>>>(
      x, xgT1, wpf1, ne1, bp1, (void*)out1, 384);
  hipMemsetAsync((void*)stats, 0, 256*sizeof(float), stream);
  k_bn_stats_bf<<<768, 256, 0, stream>>>(out1, stats, 96000, 125);
  gemm_mfma<1><<<dim3(1,750), 256, 0, stream>>>(
      AgXrow{x}, BgPk{r1wp,64}, EpRes1{out1, stats, bn1g, bn1b, r1b, 1.f/96000.f},
      (void*)out2b, 96000, 128, 64, 128);

  // ---- Phase E-part1 (consumes out2b early) ----
  k_rbar_bf<<<2000, 256, 0, stream>>>(out2b, rcw, rbar);
  gemm_mfma<0><<<dim3(1,32), 256, 0, stream>>>(
      AgF32{rbar,128}, BgPk{r2wp,128}, EpRes2{r2b, rcw, rcb}, (void*)resout, 4000, 128, 128, 128);
  hipMemsetAsync((void*)stats, 0, 256*sizeof(float), stream);
  k_bn_stats<<<32, 256, 0, stream>>>(resout, stats, 4000, 125);

  // ---- Phase C: gi on MFMA + recurrent GRU (MFMA, fused stats, bf16 out) ----
  gemm_mfma<1><<<dim3(3,750), 256, 0, stream>>>(
      AgBf16p{out2b,128}, BgPk{wihp,128}, EpBias{bih}, (void*)gi16, 96000, 384, 128, 384);
  hipMemsetAsync((void*)(stats+256), 0, 256*sizeof(float), stream);
  k_gru_mfma<<<250, 256, 0, stream>>>(gi16, whhp, bhh, hsb, stats+256);
  k_bn_apply_bf_ip<<<12000, 256, 0, stream>>>(hsb, stats+256, bgg, bgb, 3072000, 1.f/96000.f);

  // ---- Phase D: one QKV GEMM + attention ----
  gemm_mfma<1><<<dim3(3,750), 256, 0, stream>>>(
      AgConvB{hsb}, BgPk{qkvwp,384}, EpBias{qkvb}, (void*)qkv16, 96000, 384, 384, 384);
  k_attn3<<<4000, 256, 0, stream>>>(qkv16, ow, ob, fcw, fcb, out2f);

  // ---- Phase E-part2 ----
  k_bn_apply4<<<500, 256, 0, stream>>>(out2f, resout, stats, bnrg, bnrb, 128000, 1.f/4000.f, 0, 1);
  k_te<<<8, 128, 0, stream>>>(ttime, te1w, te1b, te2w, te2b, teb);
  gemm_mfma<0><<<dim3(1,32), 256, 0, stream>>>(
      AgTeAdd{out2f, teb}, BgPk{finwp,128}, EpBias{finb}, (void*)fin, 4000, 64, 128, 64);
  k_grid<<<dim3(125,8), 256, 0, stream>>>(gnm, fin, dout);
}